// Round 1
// baseline (2110.651 us; speedup 1.0000x reference)
//
#include <hip/hip_runtime.h>

#define BB 2
#define CC 64
#define HH 192
#define WW 192
#define HW 36864
#define H1 190
#define W1 190
#define HW1 36100
#define PIX (BB*HW)     // 73728
#define PIX1 (BB*HW1)   // 72200

// ---------------- weight prep: transpose [o][c][n] -> [c][n][o] ----------------
__global__ __launch_bounds__(256) void prep_weights(
    const float* __restrict__ wp, const float* __restrict__ wdc,
    const float* __restrict__ wcat, const float* __restrict__ w1,
    const float* __restrict__ w2, const float* __restrict__ gamma,
    float* __restrict__ wtp, float* __restrict__ wtdc, float* __restrict__ wtcat,
    float* __restrict__ wtw1, float* __restrict__ wtw2, float* __restrict__ gt) {
  int i = blockIdx.x * 256 + threadIdx.x;
  if (i < 10368) { int o=i/576, r=i%576, c=r/9, n=r%9; wtp[(c*9+n)*18+o]=wp[i]; return; }
  i -= 10368;
  if (i < 36864) { int o=i/576, r=i%576, c=r/9, n=r%9; wtdc[(c*9+n)*64+o]=wdc[i]; return; }
  i -= 36864;
  if (i < 73728) { int o=i/1152, r=i%1152, c=r/9, n=r%9; wtcat[(c*9+n)*64+o]=wcat[i]; return; }
  i -= 73728;
  if (i < 110592) { int l=i/36864, j=i%36864, o=j/576, r=j%576, c=r/9, n=r%9;
                    wtw1[l*36864+(c*9+n)*64+o]=w1[i]; return; }
  i -= 110592;
  if (i < 110592) { int l=i/36864, j=i%36864, o=j/576, r=j%576, c=r/9, n=r%9;
                    wtw2[l*36864+(c*9+n)*64+o]=w2[i]; return; }
  i -= 110592;
  if (i < 12288) { int l=i/4096, j=i%4096, o=j/64, c=j%64; gt[l*4096+c*64+o]=gamma[i]; }
}

// ---------------- pconv: offset = conv3x3(m_t, w_pconv) + b, pad 1 ----------------
__global__ __launch_bounds__(256) void pconv_kernel(
    const float* __restrict__ m, const float* __restrict__ wt,
    const float* __restrict__ bias, float* __restrict__ off) {
  int idx = blockIdx.x * 256 + threadIdx.x;
  if (idx >= PIX) return;
  int b = idx / HW, hw = idx % HW, h = hw / WW, w = hw % WW;
  float acc[18];
  #pragma unroll
  for (int o = 0; o < 18; ++o) acc[o] = bias[o];
  int offs[9]; float msk[9];
  #pragma unroll
  for (int n = 0; n < 9; ++n) {
    int r = h + n / 3 - 1, cc = w + n % 3 - 1;
    bool v = (r >= 0 && r < HH && cc >= 0 && cc < WW);
    int rc = min(max(r, 0), HH - 1), c2 = min(max(cc, 0), WW - 1);
    offs[n] = rc * WW + c2;
    msk[n] = v ? 1.f : 0.f;
  }
  const float* xb = m + (size_t)b * CC * HW;
  for (int c = 0; c < CC; ++c) {
    float xv[9];
    #pragma unroll
    for (int n = 0; n < 9; ++n) xv[n] = msk[n] * xb[c * HW + offs[n]];
    const float* wrow = wt + c * 9 * 18;
    #pragma unroll
    for (int n = 0; n < 9; ++n)
      #pragma unroll
      for (int o = 0; o < 18; ++o)
        acc[o] += xv[n] * wrow[n * 18 + o];
  }
  #pragma unroll
  for (int o = 0; o < 18; ++o) off[((size_t)b * 18 + o) * HW + hw] = acc[o];
}

// ---------------- deformable conv (DCNv1, matches reference bilinear exactly) ----------------
__global__ __launch_bounds__(256) void deform_kernel(
    const float* __restrict__ fr, const float* __restrict__ off,
    const float* __restrict__ wt, float* __restrict__ xout) {
  int idx = blockIdx.x * 256 + threadIdx.x;
  if (idx >= PIX) return;
  int b = idx / HW, hw = idx % HW, h = hw / WW, w = hw % WW;
  float acc[64];
  #pragma unroll
  for (int o = 0; o < 64; ++o) acc[o] = 0.f;
  const float* xb = fr + (size_t)b * CC * HW;
  for (int n = 0; n < 9; ++n) {
    float offr = off[((size_t)b * 18 + n) * HW + hw];
    float offc = off[((size_t)b * 18 + 9 + n) * HW + hw];
    float pr = (float)(h + 1 + n / 3 - 1) + offr;
    float pc = (float)(w + 1 + n % 3 - 1) + offc;
    float prc = fminf(fmaxf(pr, 0.f), 193.f);
    float pcc = fminf(fmaxf(pc, 0.f), 193.f);
    float f0r = floorf(pr), f0c = floorf(pc);
    int qr0 = (int)fminf(fmaxf(f0r, 0.f), 193.f);
    int qc0 = (int)fminf(fmaxf(f0c, 0.f), 193.f);
    int qr1 = (int)fminf(fmaxf(f0r + 1.f, 0.f), 193.f);
    int qc1 = (int)fminf(fmaxf(f0c + 1.f, 0.f), 193.f);
    float dr0 = 1.f + ((float)qr0 - prc);   // (1+(qr0-pr))
    float dr1 = 1.f - ((float)qr1 - prc);   // (1-(qr1-pr))
    float dc0 = 1.f + ((float)qc0 - pcc);
    float dc1 = 1.f - ((float)qc1 - pcc);
    // corners: lt(qr0,qc0) rb(qr1,qc1) lb(qr0,qc1) rt(qr1,qc0), gathered from zero-padded (pad=1)
    int o0, o1, o2, o3; float g0, g1, g2, g3;
    {
      bool v = (qr0 >= 1 && qr0 <= 192 && qc0 >= 1 && qc0 <= 192);
      o0 = min(max(qr0 - 1, 0), 191) * WW + min(max(qc0 - 1, 0), 191);
      g0 = v ? dr0 * dc0 : 0.f;
    }
    {
      bool v = (qr1 >= 1 && qr1 <= 192 && qc1 >= 1 && qc1 <= 192);
      o1 = min(max(qr1 - 1, 0), 191) * WW + min(max(qc1 - 1, 0), 191);
      g1 = v ? dr1 * dc1 : 0.f;
    }
    {
      bool v = (qr0 >= 1 && qr0 <= 192 && qc1 >= 1 && qc1 <= 192);
      o2 = min(max(qr0 - 1, 0), 191) * WW + min(max(qc1 - 1, 0), 191);
      g2 = v ? dr0 * dc1 : 0.f;
    }
    {
      bool v = (qr1 >= 1 && qr1 <= 192 && qc0 >= 1 && qc0 <= 192);
      o3 = min(max(qr1 - 1, 0), 191) * WW + min(max(qc0 - 1, 0), 191);
      g3 = v ? dr1 * dc0 : 0.f;
    }
    for (int c = 0; c < 64; ++c) {
      const float* xc = xb + c * HW;
      float v = g0 * xc[o0] + g1 * xc[o1] + g2 * xc[o2] + g3 * xc[o3];
      const float* wv = wt + (c * 9 + n) * 64;
      #pragma unroll
      for (int o = 0; o < 64; ++o) acc[o] += v * wv[o];
    }
  }
  #pragma unroll
  for (int o = 0; o < 64; ++o) xout[((size_t)b * 64 + o) * HW + hw] = acc[o];
}

// ---------------- conv_cat: conv3x3(concat([x, f_r]), w_cat) + b, pad 1 ----------------
__global__ __launch_bounds__(256) void convcat_kernel(
    const float* __restrict__ x, const float* __restrict__ fr,
    const float* __restrict__ wt, const float* __restrict__ bias,
    float* __restrict__ y) {
  int idx = blockIdx.x * 256 + threadIdx.x;
  if (idx >= PIX) return;
  int b = idx / HW, hw = idx % HW, h = hw / WW, w = hw % WW;
  float acc[64];
  #pragma unroll
  for (int o = 0; o < 64; ++o) acc[o] = bias[o];
  int offs[9]; float msk[9];
  #pragma unroll
  for (int n = 0; n < 9; ++n) {
    int r = h + n / 3 - 1, cc = w + n % 3 - 1;
    bool v = (r >= 0 && r < HH && cc >= 0 && cc < WW);
    offs[n] = min(max(r, 0), HH - 1) * WW + min(max(cc, 0), WW - 1);
    msk[n] = v ? 1.f : 0.f;
  }
  const float* src0 = x + (size_t)b * CC * HW;
  const float* src1 = fr + (size_t)b * CC * HW;
  for (int half = 0; half < 2; ++half) {
    const float* s = half ? src1 : src0;
    for (int c = 0; c < 64; ++c) {
      float xv[9];
      #pragma unroll
      for (int n = 0; n < 9; ++n) xv[n] = msk[n] * s[c * HW + offs[n]];
      const float* wrow = wt + ((half * 64 + c) * 9) * 64;
      #pragma unroll
      for (int n = 0; n < 9; ++n)
        #pragma unroll
        for (int o = 0; o < 64; ++o)
          acc[o] += xv[n] * wrow[n * 64 + o];
    }
  }
  #pragma unroll
  for (int o = 0; o < 64; ++o) y[((size_t)b * 64 + o) * HW + hw] = acc[o];
}

// ---------------- resblock conv1 (no pad, 192->190) + GDN + CELU ----------------
__global__ __launch_bounds__(256) void conv1gdn_kernel(
    const float* __restrict__ y, const float* __restrict__ wt,
    const float* __restrict__ beta, const float* __restrict__ gt,
    float* __restrict__ hbuf) {
  int idx = blockIdx.x * 256 + threadIdx.x;
  if (idx >= PIX1) return;
  int b = idx / HW1, r = idx % HW1, h = r / W1, w = r % W1;
  float acc[64];
  #pragma unroll
  for (int o = 0; o < 64; ++o) acc[o] = 0.f;
  const float* yb = y + (size_t)b * CC * HW;
  for (int c = 0; c < 64; ++c) {
    const float* base = yb + c * HW + h * WW + w;
    float xv[9];
    #pragma unroll
    for (int kh = 0; kh < 3; ++kh)
      #pragma unroll
      for (int kw = 0; kw < 3; ++kw)
        xv[kh * 3 + kw] = base[kh * WW + kw];
    const float* wrow = wt + c * 576;
    #pragma unroll
    for (int n = 0; n < 9; ++n)
      #pragma unroll
      for (int o = 0; o < 64; ++o)
        acc[o] += xv[n] * wrow[n * 64 + o];
  }
  // GDN: norm[o] = beta[o] + sum_c gamma[o,c] * acc[c]^2 ; v = acc/sqrt(norm) ; CELU
  float nrm[64];
  #pragma unroll
  for (int o = 0; o < 64; ++o) nrm[o] = beta[o];
  for (int c = 0; c < 64; ++c) {
    float s = acc[c] * acc[c];
    const float* g = gt + c * 64;
    #pragma unroll
    for (int o = 0; o < 64; ++o) nrm[o] += s * g[o];
  }
  #pragma unroll
  for (int o = 0; o < 64; ++o) {
    float v = acc[o] / sqrtf(nrm[o]);
    v = v > 0.f ? v : expf(v) - 1.f;
    hbuf[((size_t)b * 64 + o) * HW1 + r] = v;
  }
}

// ---------------- resblock conv2 (pad 2, 190->192) + residual (+ final x) ----------------
template <bool LAST>
__global__ __launch_bounds__(256) void conv2_kernel(
    const float* __restrict__ hbuf, const float* __restrict__ wt,
    const float* __restrict__ xres, float* __restrict__ y,
    float* __restrict__ out) {
  int idx = blockIdx.x * 256 + threadIdx.x;
  if (idx >= PIX) return;
  int b = idx / HW, hw = idx % HW, h = hw / WW, w = hw % WW;
  float acc[64];
  #pragma unroll
  for (int o = 0; o < 64; ++o) acc[o] = 0.f;
  int offs[9]; float msk[9];
  #pragma unroll
  for (int n = 0; n < 9; ++n) {
    int r = h + n / 3 - 2, cc = w + n % 3 - 2;
    bool v = (r >= 0 && r < H1 && cc >= 0 && cc < W1);
    offs[n] = min(max(r, 0), H1 - 1) * W1 + min(max(cc, 0), W1 - 1);
    msk[n] = v ? 1.f : 0.f;
  }
  const float* hb = hbuf + (size_t)b * CC * HW1;
  for (int c = 0; c < 64; ++c) {
    float xv[9];
    #pragma unroll
    for (int n = 0; n < 9; ++n) xv[n] = msk[n] * hb[c * HW1 + offs[n]];
    const float* wrow = wt + c * 576;
    #pragma unroll
    for (int n = 0; n < 9; ++n)
      #pragma unroll
      for (int o = 0; o < 64; ++o)
        acc[o] += xv[n] * wrow[n * 64 + o];
  }
  #pragma unroll
  for (int o = 0; o < 64; ++o) {
    size_t p = ((size_t)b * 64 + o) * HW + hw;
    float v = acc[o] + y[p];
    if (LAST) out[p] = v + xres[p];
    else y[p] = v;
  }
}

extern "C" void kernel_launch(void* const* d_in, const int* in_sizes, int n_in,
                              void* d_out, int out_size, void* d_ws, size_t ws_size,
                              hipStream_t stream) {
  const float* f_r      = (const float*)d_in[0];
  const float* m_t      = (const float*)d_in[1];
  const float* w_pconv  = (const float*)d_in[2];
  const float* b_pconv  = (const float*)d_in[3];
  const float* w_dc     = (const float*)d_in[4];
  const float* w_cat    = (const float*)d_in[5];
  const float* b_cat    = (const float*)d_in[6];
  const float* rb_w1    = (const float*)d_in[7];
  const float* rb_w2    = (const float*)d_in[8];
  const float* rb_beta  = (const float*)d_in[9];
  const float* rb_gamma = (const float*)d_in[10];
  float* out = (float*)d_out;

  float* ws    = (float*)d_ws;
  float* off   = ws;                   // 2*18*36864      = 1327104
  float* xbuf  = off   + 1327104;      // 2*64*36864      = 4718592
  float* ybuf  = xbuf  + 4718592;      // 4718592
  float* hbuf  = ybuf  + 4718592;      // 2*64*36100      = 4620800
  float* wtp   = hbuf  + 4620800;      // 10368
  float* wtdc  = wtp   + 10368;        // 36864
  float* wtcat = wtdc  + 36864;        // 73728
  float* wtw1  = wtcat + 73728;        // 110592
  float* wtw2  = wtw1  + 110592;       // 110592
  float* gt    = wtw2  + 110592;       // 12288   (total ~63 MB)

  prep_weights<<<(354432 + 255) / 256, 256, 0, stream>>>(
      w_pconv, w_dc, w_cat, rb_w1, rb_w2, rb_gamma, wtp, wtdc, wtcat, wtw1, wtw2, gt);
  pconv_kernel<<<(PIX + 255) / 256, 256, 0, stream>>>(m_t, wtp, b_pconv, off);
  deform_kernel<<<(PIX + 255) / 256, 256, 0, stream>>>(f_r, off, wtdc, xbuf);
  convcat_kernel<<<(PIX + 255) / 256, 256, 0, stream>>>(xbuf, f_r, wtcat, b_cat, ybuf);
  for (int l = 0; l < 3; ++l) {
    conv1gdn_kernel<<<(PIX1 + 255) / 256, 256, 0, stream>>>(
        ybuf, wtw1 + l * 36864, rb_beta + l * 64, gt + l * 4096, hbuf);
    if (l < 2)
      conv2_kernel<false><<<(PIX + 255) / 256, 256, 0, stream>>>(
          hbuf, wtw2 + l * 36864, xbuf, ybuf, out);
    else
      conv2_kernel<true><<<(PIX + 255) / 256, 256, 0, stream>>>(
          hbuf, wtw2 + l * 36864, xbuf, ybuf, out);
  }
}

// Round 2
// 1179.555 us; speedup vs baseline: 1.7894x; 1.7894x over previous
//
#include <hip/hip_runtime.h>

typedef __attribute__((ext_vector_type(8))) __bf16 bf16x8;
typedef __attribute__((ext_vector_type(4))) __bf16 bf16x4;
typedef __attribute__((ext_vector_type(16))) float f32x16;
typedef __attribute__((ext_vector_type(4))) float f32x4;

#define HH 192
#define WW 192
#define HW 36864
#define HW1 36100
#define PIX 73728

#define COLSTRIDE 144            // bytes per staged col: 64 bf16 = 128B + 16B pad (16B-aligned)
#define ROWPITCH (66 * COLSTRIDE) // 9504
#define GDNPITCH 144             // v^2 tile: [256 p][64+8 c] bf16
#define TREG 8704                // per-wave transpose region: 32 cols x 68 floats x 4B
#define SMEM_BYTES 57024         // max(6*ROWPITCH, 256*GDNPITCH, 4*TREG)

__device__ inline f32x16 mfma32(bf16x8 a, bf16x8 b, f32x16 c) {
  return __builtin_amdgcn_mfma_f32_32x32x16_bf16(a, b, c, 0, 0, 0);
}

__device__ inline f32x16 zero16() {
  f32x16 z;
#pragma unroll
  for (int e = 0; e < 16; ++e) z[e] = 0.f;
  return z;
}

// ---------------- weight prep ----------------
// MFMA A-fragment tiled layout: per (n, kc, ot) a 1KB block of 64 lanes x 16B:
//   elem((lane,j)) = W[o = ot*32 + (lane&31)][c = kc*16 + (lane>>5)*8 + j]
__global__ __launch_bounds__(256) void prep_weights(
    const float* __restrict__ wp, const float* __restrict__ wdc,
    const float* __restrict__ wcat, const float* __restrict__ w1,
    const float* __restrict__ w2, const float* __restrict__ gamma,
    float* __restrict__ wtp, float* __restrict__ wtdc,
    __bf16* __restrict__ wcatA, __bf16* __restrict__ w1A,
    __bf16* __restrict__ w2A, __bf16* __restrict__ gA) {
  int i = blockIdx.x * 256 + threadIdx.x;
  if (i < 10368) { int o=i/576, r=i%576, c=r/9, n=r%9; wtp[(c*9+n)*18+o]=wp[i]; return; }
  i -= 10368;
  if (i < 36864) { int o=i/576, r=i%576, c=r/9, n=r%9; wtdc[(c*9+n)*64+o]=wdc[i]; return; }
  i -= 36864;
  if (i < 73728) {  // wcatA: Cin=128, KC=8
    int d = i, j = d & 7; d >>= 3; int lane = d & 63; d >>= 6; int ot = d & 1; d >>= 1;
    int kc = d & 7; int n = d >> 3;
    int o = ot*32 + (lane & 31), c = kc*16 + ((lane >> 5) << 3) + j;
    wcatA[i] = (__bf16)wcat[(o*128 + c)*9 + n];
    return;
  }
  i -= 73728;
  if (i < 110592) {  // w1A: 3 layers, Cin=64, KC=4
    int l = i / 36864, di = i % 36864, d = di;
    int j = d & 7; d >>= 3; int lane = d & 63; d >>= 6; int ot = d & 1; d >>= 1;
    int kc = d & 3; int n = d >> 2;
    int o = ot*32 + (lane & 31), c = kc*16 + ((lane >> 5) << 3) + j;
    w1A[l*36864 + di] = (__bf16)w1[l*36864 + (o*64 + c)*9 + n];
    return;
  }
  i -= 110592;
  if (i < 110592) {  // w2A
    int l = i / 36864, di = i % 36864, d = di;
    int j = d & 7; d >>= 3; int lane = d & 63; d >>= 6; int ot = d & 1; d >>= 1;
    int kc = d & 3; int n = d >> 2;
    int o = ot*32 + (lane & 31), c = kc*16 + ((lane >> 5) << 3) + j;
    w2A[l*36864 + di] = (__bf16)w2[l*36864 + (o*64 + c)*9 + n];
    return;
  }
  i -= 110592;
  if (i < 12288) {  // gA: 3 layers, K=64 GEMM A-tiles (no n dim)
    int l = i / 4096, di = i % 4096, d = di;
    int j = d & 7; d >>= 3; int lane = d & 63; d >>= 6; int ot = d & 1; d >>= 1;
    int kc = d & 3;
    int o = ot*32 + (lane & 31), c = kc*16 + ((lane >> 5) << 3) + j;
    gA[l*4096 + di] = (__bf16)gamma[l*4096 + o*64 + c];
  }
}

// ---------------- pconv (unchanged fp32, validated in R0) ----------------
__global__ __launch_bounds__(256) void pconv_kernel(
    const float* __restrict__ m, const float* __restrict__ wt,
    const float* __restrict__ bias, float* __restrict__ off) {
  int idx = blockIdx.x * 256 + threadIdx.x;
  if (idx >= PIX) return;
  int b = idx / HW, hw = idx % HW, h = hw / WW, w = hw % WW;
  float acc[18];
#pragma unroll
  for (int o = 0; o < 18; ++o) acc[o] = bias[o];
  int offs[9]; float msk[9];
#pragma unroll
  for (int n = 0; n < 9; ++n) {
    int r = h + n / 3 - 1, cc = w + n % 3 - 1;
    bool v = (r >= 0 && r < HH && cc >= 0 && cc < WW);
    offs[n] = min(max(r, 0), HH - 1) * WW + min(max(cc, 0), WW - 1);
    msk[n] = v ? 1.f : 0.f;
  }
  const float* xb = m + (size_t)b * 64 * HW;
  for (int c = 0; c < 64; ++c) {
    float xv[9];
#pragma unroll
    for (int n = 0; n < 9; ++n) xv[n] = msk[n] * xb[c * HW + offs[n]];
    const float* wrow = wt + c * 9 * 18;
#pragma unroll
    for (int n = 0; n < 9; ++n)
#pragma unroll
      for (int o = 0; o < 18; ++o)
        acc[o] += xv[n] * wrow[n * 18 + o];
  }
#pragma unroll
  for (int o = 0; o < 18; ++o) off[((size_t)b * 18 + o) * HW + hw] = acc[o];
}

// ---------------- deformable conv: 32 outputs/thread, writes cat NHWC c0..63 ----------------
__global__ __launch_bounds__(256) void deform_kernel(
    const float* __restrict__ fr, const float* __restrict__ off,
    const float* __restrict__ wt, float* __restrict__ cat) {
  int idx = blockIdx.x * 256 + threadIdx.x;
  if (idx >= 2 * PIX) return;
  int g = idx / PIX, pix = idx - g * PIX;
  int b = pix / HW, hw = pix % HW, h = hw / WW, w = hw % WW;
  f32x4 acc[8];
#pragma unroll
  for (int o4 = 0; o4 < 8; ++o4) acc[o4] = (f32x4){0.f, 0.f, 0.f, 0.f};
  const float* xb = fr + (size_t)b * 64 * HW;
  for (int n = 0; n < 9; ++n) {
    float offr = off[((size_t)b * 18 + n) * HW + hw];
    float offc = off[((size_t)b * 18 + 9 + n) * HW + hw];
    float pr = (float)(h + 1 + n / 3 - 1) + offr;
    float pc = (float)(w + 1 + n % 3 - 1) + offc;
    float prc = fminf(fmaxf(pr, 0.f), 193.f);
    float pcc = fminf(fmaxf(pc, 0.f), 193.f);
    float f0r = floorf(pr), f0c = floorf(pc);
    int qr0 = (int)fminf(fmaxf(f0r, 0.f), 193.f);
    int qc0 = (int)fminf(fmaxf(f0c, 0.f), 193.f);
    int qr1 = (int)fminf(fmaxf(f0r + 1.f, 0.f), 193.f);
    int qc1 = (int)fminf(fmaxf(f0c + 1.f, 0.f), 193.f);
    float dr0 = 1.f + ((float)qr0 - prc);
    float dr1 = 1.f - ((float)qr1 - prc);
    float dc0 = 1.f + ((float)qc0 - pcc);
    float dc1 = 1.f - ((float)qc1 - pcc);
    int o0, o1, o2, o3; float g0, g1, g2, g3;
    { bool v = (qr0 >= 1 && qr0 <= 192 && qc0 >= 1 && qc0 <= 192);
      o0 = min(max(qr0-1,0),191)*WW + min(max(qc0-1,0),191); g0 = v ? dr0*dc0 : 0.f; }
    { bool v = (qr1 >= 1 && qr1 <= 192 && qc1 >= 1 && qc1 <= 192);
      o1 = min(max(qr1-1,0),191)*WW + min(max(qc1-1,0),191); g1 = v ? dr1*dc1 : 0.f; }
    { bool v = (qr0 >= 1 && qr0 <= 192 && qc1 >= 1 && qc1 <= 192);
      o2 = min(max(qr0-1,0),191)*WW + min(max(qc1-1,0),191); g2 = v ? dr0*dc1 : 0.f; }
    { bool v = (qr1 >= 1 && qr1 <= 192 && qc0 >= 1 && qc0 <= 192);
      o3 = min(max(qr1-1,0),191)*WW + min(max(qc0-1,0),191); g3 = v ? dr1*dc0 : 0.f; }
    for (int c = 0; c < 64; ++c) {
      const float* xc = xb + c * HW;
      float v = g0 * xc[o0] + g1 * xc[o1] + g2 * xc[o2] + g3 * xc[o3];
      const float* wv = wt + (c * 9 + n) * 64 + g * 32;
#pragma unroll
      for (int o4 = 0; o4 < 8; ++o4) {
        f32x4 wq = *(const f32x4*)(wv + o4 * 4);
        acc[o4] += v * wq;
      }
    }
  }
  float* dp = cat + (size_t)pix * 128 + g * 32;
#pragma unroll
  for (int o4 = 0; o4 < 8; ++o4) *(f32x4*)(dp + o4 * 4) = acc[o4];
}

// ---------------- f_r NCHW -> cat NHWC channels 64..127 (tiled transpose) ----------------
__global__ __launch_bounds__(256) void fr_to_cat(const float* __restrict__ fr,
                                                 float* __restrict__ cat) {
  __shared__ __align__(16) float t[64 * 68];
  int b = blockIdx.x / 576, p0 = (blockIdx.x % 576) * 64;
  int tid = threadIdx.x;
  int c = tid >> 2, ch = (tid & 3) * 16;
  const float* sp = fr + ((size_t)b * 64 + c) * HW + p0 + ch;
#pragma unroll
  for (int q = 0; q < 4; ++q) {
    f32x4 v = *(const f32x4*)(sp + q * 4);
#pragma unroll
    for (int e = 0; e < 4; ++e) t[(ch + q * 4 + e) * 68 + c] = v[e];
  }
  __syncthreads();
  int p = tid >> 2, cq = (tid & 3) * 16;
  float* dp = cat + ((size_t)b * HW + p0 + p) * 128 + 64 + cq;
#pragma unroll
  for (int q = 0; q < 4; ++q) *(f32x4*)(dp + q * 4) = *(const f32x4*)(&t[p * 68 + cq + q * 4]);
}

// ---------------- staging: fp32 NHWC source -> bf16 LDS tile (6 rows x 66 cols x 64c) ----------------
__device__ inline void stage_f32(const float* __restrict__ src, int C, int cbase,
                                 int srcH, int srcW, int row0, int col0,
                                 unsigned char* lds) {
  for (int i = threadIdx.x; i < 6 * 66 * 16; i += 256) {
    int r = i / 1056, rem = i - r * 1056, j = rem >> 4, q = rem & 15;
    int gr = row0 + r, gc = col0 + j;
    f32x4 v = {0.f, 0.f, 0.f, 0.f};
    if (gr >= 0 && gr < srcH && gc >= 0 && gc < srcW)
      v = *(const f32x4*)(src + ((size_t)gr * srcW + gc) * C + cbase + q * 4);
    bf16x4 o;
#pragma unroll
    for (int e = 0; e < 4; ++e) o[e] = (__bf16)v[e];
    *(bf16x4*)(lds + r * ROWPITCH + j * COLSTRIDE + q * 8) = o;
  }
}

__device__ inline void stage_bf16(const __bf16* __restrict__ src,
                                  int srcH, int srcW, int row0, int col0,
                                  unsigned char* lds) {
  for (int i = threadIdx.x; i < 6 * 66 * 8; i += 256) {
    int r = i / 528, rem = i - r * 528, j = rem >> 3, u = rem & 7;
    int gr = row0 + r, gc = col0 + j;
    bf16x8 v;
#pragma unroll
    for (int e = 0; e < 8; ++e) v[e] = (__bf16)0.f;
    if (gr >= 0 && gr < srcH && gc >= 0 && gc < srcW)
      v = *(const bf16x8*)(src + ((size_t)gr * srcW + gc) * 64 + u * 8);
    *(bf16x8*)(lds + r * ROWPITCH + j * COLSTRIDE + u * 16) = v;
  }
}

// ---------------- MFMA K-loop: 9 taps x 4 K16-steps, wave tile 64o x 64p ----------------
template <int KC, int KOFFA>
__device__ inline void kloop(const __bf16* __restrict__ wA,
                             const unsigned char* __restrict__ lds, int wp,
                             f32x16 acc[2][2]) {
  const int lane = threadIdx.x & 63;
  const int m = lane & 31;
  const int kh8 = (lane >> 5) << 3;
  const __bf16* aB = wA + lane * 8;
  const unsigned char* bB = lds + wp * ROWPITCH + m * COLSTRIDE + kh8 * 2;
#pragma unroll
  for (int n = 0; n < 9; ++n) {
    const int kh = n / 3, kw = n % 3;
#pragma unroll
    for (int kc = 0; kc < 4; ++kc) {
      bf16x8 a0 = *(const bf16x8*)(aB + ((n * KC + KOFFA + kc) * 2 + 0) * 512);
      bf16x8 a1 = *(const bf16x8*)(aB + ((n * KC + KOFFA + kc) * 2 + 1) * 512);
      const unsigned char* bp = bB + kh * ROWPITCH + kw * COLSTRIDE + kc * 32;
      bf16x8 b0 = *(const bf16x8*)(bp);
      bf16x8 b1 = *(const bf16x8*)(bp + 32 * COLSTRIDE);
      acc[0][0] = mfma32(a0, b0, acc[0][0]);
      acc[0][1] = mfma32(a0, b1, acc[0][1]);
      acc[1][0] = mfma32(a1, b0, acc[1][0]);
      acc[1][1] = mfma32(a1, b1, acc[1][1]);
    }
  }
}

// ---------------- epilogue helpers: per-wave half-transpose through LDS ----------------
__device__ inline void acchalf_to_lds(const f32x16 acc[2][2], int pt, unsigned char* reg) {
  int lane = threadIdx.x & 63;
  int colb = lane & 31, half = lane >> 5;
#pragma unroll
  for (int ot = 0; ot < 2; ++ot)
#pragma unroll
    for (int g = 0; g < 4; ++g) {
      int o = ot * 32 + half * 4 + g * 8;
      f32x4 v;
      v[0] = acc[ot][pt][g * 4 + 0]; v[1] = acc[ot][pt][g * 4 + 1];
      v[2] = acc[ot][pt][g * 4 + 2]; v[3] = acc[ot][pt][g * 4 + 3];
      *(f32x4*)(reg + (colb * 68 + o) * 4) = v;
    }
}

__device__ inline void read_half(const unsigned char* reg, f32x4 v[8]) {
  int lane = threadIdx.x & 63;
  int col = lane & 31, ch = (lane >> 5) * 32;
#pragma unroll
  for (int q = 0; q < 8; ++q)
    v[q] = *(const f32x4*)(reg + (col * 68 + ch + q * 4) * 4);
}

// ---------------- convcat: Cin=128 (two 64c chunks), +bias, -> y fp32 NHWC ----------------
__global__ __launch_bounds__(256, 1) void convcat_mfma(
    const float* __restrict__ cat, const __bf16* __restrict__ wA,
    const float* __restrict__ bias, float* __restrict__ y) {
  __shared__ __align__(16) unsigned char smem[SMEM_BYTES];
  int b = blockIdx.x / 144, r = blockIdx.x % 144, rt = r / 3, ct = r % 3;
  int h0 = rt * 4, w0 = ct * 64;
  int wid = threadIdx.x >> 6, lane = threadIdx.x & 63;
  const float* src = cat + (size_t)b * HW * 128;
  f32x16 acc[2][2];
  acc[0][0] = zero16(); acc[0][1] = zero16(); acc[1][0] = zero16(); acc[1][1] = zero16();
  stage_f32(src, 128, 0, 192, 192, h0 - 1, w0 - 1, smem);
  __syncthreads();
  kloop<8, 0>(wA, smem, wid, acc);
  __syncthreads();
  stage_f32(src, 128, 64, 192, 192, h0 - 1, w0 - 1, smem);
  __syncthreads();
  kloop<8, 4>(wA, smem, wid, acc);
  __syncthreads();
  unsigned char* reg = smem + wid * TREG;
  float* dsty = y + ((size_t)b * HW + (size_t)(h0 + wid) * 192 + w0) * 64;
  int col = lane & 31, ch = (lane >> 5) * 32;
#pragma unroll
  for (int pt = 0; pt < 2; ++pt) {
    acchalf_to_lds(acc, pt, reg);
    __builtin_amdgcn_s_waitcnt(0);
    f32x4 v[8];
    read_half(reg, v);
    float* dp = dsty + (size_t)(pt * 32 + col) * 64 + ch;
#pragma unroll
    for (int q = 0; q < 8; ++q) {
      f32x4 bv = *(const f32x4*)(bias + ch + q * 4);
      v[q] += bv;
      *(f32x4*)(dp + q * 4) = v[q];
    }
  }
}

// ---------------- conv1 + GDN + CELU: y fp32 NHWC -> h bf16 NHWC (190x190) ----------------
__global__ __launch_bounds__(256, 1) void conv1gdn_mfma(
    const float* __restrict__ y, const __bf16* __restrict__ w1A,
    const __bf16* __restrict__ gA, const float* __restrict__ beta,
    __bf16* __restrict__ hbuf) {
  __shared__ __align__(16) unsigned char smem[SMEM_BYTES];
  int b = blockIdx.x / 144, r = blockIdx.x % 144, rt = r / 3, ct = r % 3;
  int h0 = rt * 4, w0 = ct * 64;
  int wid = threadIdx.x >> 6, lane = threadIdx.x & 63;
  int colb = lane & 31, half = lane >> 5;
  const int kh8 = half << 3;
  const float* src = y + (size_t)b * HW * 64;
  f32x16 acc[2][2];
  acc[0][0] = zero16(); acc[0][1] = zero16(); acc[1][0] = zero16(); acc[1][1] = zero16();
  stage_f32(src, 64, 0, 192, 192, h0, w0, smem);
  __syncthreads();
  kloop<4, 0>(w1A, smem, wid, acc);
  __syncthreads();
  // v^2 -> LDS [p][c] bf16 tile
#pragma unroll
  for (int ot = 0; ot < 2; ++ot)
#pragma unroll
    for (int pt = 0; pt < 2; ++pt)
#pragma unroll
      for (int g = 0; g < 4; ++g) {
        int o = ot * 32 + half * 4 + g * 8;
        int p = wid * 64 + pt * 32 + colb;
        bf16x4 s;
#pragma unroll
        for (int e = 0; e < 4; ++e) {
          float x = acc[ot][pt][g * 4 + e];
          s[e] = (__bf16)(x * x);
        }
        *(bf16x4*)(smem + p * GDNPITCH + o * 2) = s;
      }
  __syncthreads();
  // norm GEMM: norm = gamma (64x64) * v^2 (64 x 64p)
  f32x16 nacc[2][2];
  nacc[0][0] = zero16(); nacc[0][1] = zero16(); nacc[1][0] = zero16(); nacc[1][1] = zero16();
  {
    const __bf16* gaB = gA + lane * 8;
    const unsigned char* gb = smem + (wid * 64 + colb) * GDNPITCH + kh8 * 2;
#pragma unroll
    for (int kc = 0; kc < 4; ++kc) {
      bf16x8 a0 = *(const bf16x8*)(gaB + (kc * 2 + 0) * 512);
      bf16x8 a1 = *(const bf16x8*)(gaB + (kc * 2 + 1) * 512);
      bf16x8 b0 = *(const bf16x8*)(gb + kc * 32);
      bf16x8 b1 = *(const bf16x8*)(gb + 32 * GDNPITCH + kc * 32);
      nacc[0][0] = mfma32(a0, b0, nacc[0][0]);
      nacc[0][1] = mfma32(a0, b1, nacc[0][1]);
      nacc[1][0] = mfma32(a1, b0, nacc[1][0]);
      nacc[1][1] = mfma32(a1, b1, nacc[1][1]);
    }
  }
  // h = celu(v * rsqrt(beta + norm))
#pragma unroll
  for (int ot = 0; ot < 2; ++ot)
#pragma unroll
    for (int g = 0; g < 4; ++g) {
      f32x4 bet = *(const f32x4*)(beta + ot * 32 + half * 4 + g * 8);
#pragma unroll
      for (int pt = 0; pt < 2; ++pt)
#pragma unroll
        for (int e = 0; e < 4; ++e) {
          float nv = bet[e] + nacc[ot][pt][g * 4 + e];
          float hv = acc[ot][pt][g * 4 + e] * rsqrtf(nv);
          hv = hv > 0.f ? hv : expf(hv) - 1.f;
          acc[ot][pt][g * 4 + e] = hv;
        }
    }
  __syncthreads();  // gdn tile done being read; transpose regions may overlap it
  unsigned char* reg = smem + wid * TREG;
  int hr = h0 + wid;
  bool rowok = hr < 190;
  int ch = half * 32;
#pragma unroll
  for (int pt = 0; pt < 2; ++pt) {
    acchalf_to_lds(acc, pt, reg);
    __builtin_amdgcn_s_waitcnt(0);
    f32x4 v[8];
    read_half(reg, v);
    int wcol = w0 + pt * 32 + colb;
    if (rowok && wcol < 190) {
      __bf16* dp = hbuf + ((size_t)b * HW1 + (size_t)hr * 190 + wcol) * 64 + ch;
#pragma unroll
      for (int q = 0; q < 8; ++q) {
        bf16x4 o;
#pragma unroll
        for (int e = 0; e < 4; ++e) o[e] = (__bf16)v[q][e];
        *(bf16x4*)(dp + q * 4) = o;
      }
    }
  }
}

// ---------------- conv2 (pad 2) + residual; LAST adds x and writes NCHW out ----------------
template <bool LAST>
__global__ __launch_bounds__(256, 1) void conv2_mfma(
    const __bf16* __restrict__ hbuf, const __bf16* __restrict__ w2A,
    const float* __restrict__ cat, float* __restrict__ y,
    float* __restrict__ out) {
  __shared__ __align__(16) unsigned char smem[SMEM_BYTES];
  int b = blockIdx.x / 144, r = blockIdx.x % 144, rt = r / 3, ct = r % 3;
  int h0 = rt * 4, w0 = ct * 64;
  int wid = threadIdx.x >> 6, lane = threadIdx.x & 63;
  const __bf16* src = hbuf + (size_t)b * HW1 * 64;
  f32x16 acc[2][2];
  acc[0][0] = zero16(); acc[0][1] = zero16(); acc[1][0] = zero16(); acc[1][1] = zero16();
  stage_bf16(src, 190, 190, h0 - 2, w0 - 2, smem);
  __syncthreads();
  kloop<4, 0>(w2A, smem, wid, acc);
  __syncthreads();
  unsigned char* reg = smem + wid * TREG;
  int col = lane & 31, ch = (lane >> 5) * 32;
  size_t pixbase = (size_t)b * HW + (size_t)(h0 + wid) * 192 + w0;
#pragma unroll
  for (int pt = 0; pt < 2; ++pt) {
    acchalf_to_lds(acc, pt, reg);
    __builtin_amdgcn_s_waitcnt(0);
    f32x4 v[8];
    read_half(reg, v);
    size_t pix = pixbase + pt * 32 + col;
    float* yp = y + pix * 64 + ch;
#pragma unroll
    for (int q = 0; q < 8; ++q) v[q] += *(const f32x4*)(yp + q * 4);
    if (!LAST) {
#pragma unroll
      for (int q = 0; q < 8; ++q) *(f32x4*)(yp + q * 4) = v[q];
    } else {
      const float* xp = cat + pix * 128 + ch;
#pragma unroll
      for (int q = 0; q < 8; ++q) v[q] += *(const f32x4*)(xp + q * 4);
      // write back to LDS, then col-major read for NCHW store
#pragma unroll
      for (int q = 0; q < 8; ++q)
        *(f32x4*)(reg + (col * 68 + ch + q * 4) * 4) = v[q];
      __builtin_amdgcn_s_waitcnt(0);
      int o = lane;
      float* op = out + ((size_t)b * 64 + o) * HW + (size_t)(h0 + wid) * 192 + w0 + pt * 32;
#pragma unroll
      for (int q = 0; q < 8; ++q) {
        f32x4 s;
#pragma unroll
        for (int e = 0; e < 4; ++e)
          s[e] = *(const float*)(reg + ((q * 4 + e) * 68 + o) * 4);
        *(f32x4*)(op + q * 4) = s;
      }
    }
  }
}

extern "C" void kernel_launch(void* const* d_in, const int* in_sizes, int n_in,
                              void* d_out, int out_size, void* d_ws, size_t ws_size,
                              hipStream_t stream) {
  const float* f_r      = (const float*)d_in[0];
  const float* m_t      = (const float*)d_in[1];
  const float* w_pconv  = (const float*)d_in[2];
  const float* b_pconv  = (const float*)d_in[3];
  const float* w_dc     = (const float*)d_in[4];
  const float* w_cat    = (const float*)d_in[5];
  const float* b_cat    = (const float*)d_in[6];
  const float* rb_w1    = (const float*)d_in[7];
  const float* rb_w2    = (const float*)d_in[8];
  const float* rb_beta  = (const float*)d_in[9];
  const float* rb_gamma = (const float*)d_in[10];
  float* out = (float*)d_out;

  float* ws = (float*)d_ws;
  // h-buffer (bf16, 4,620,800 elems) aliases the offset buffer (1,327,104 f32):
  // off is fully consumed by deform before conv1 first writes h.
  float*  off   = ws;
  __bf16* hbuf  = (__bf16*)ws;
  float*  cat   = ws + 2310400;          // [2][192][192][128] fp32
  float*  ybuf  = cat + 9437184;         // [2][192][192][64]  fp32
  float*  wtp   = ybuf + 4718592;        // 10368
  float*  wtdc  = wtp + 10368;           // 36864
  __bf16* wcatA = (__bf16*)(wtdc + 36864);            // 73728 bf16
  __bf16* w1A   = (__bf16*)(wtdc + 36864 + 36864);    // 110592 bf16
  __bf16* w2A   = (__bf16*)(wtdc + 36864 + 36864 + 55296);
  __bf16* gA    = (__bf16*)(wtdc + 36864 + 36864 + 55296 + 55296);

  prep_weights<<<1385, 256, 0, stream>>>(w_pconv, w_dc, w_cat, rb_w1, rb_w2, rb_gamma,
                                         wtp, wtdc, wcatA, w1A, w2A, gA);
  pconv_kernel<<<288, 256, 0, stream>>>(m_t, wtp, b_pconv, off);
  deform_kernel<<<576, 256, 0, stream>>>(f_r, off, wtdc, cat);
  fr_to_cat<<<1152, 256, 0, stream>>>(f_r, cat);
  convcat_mfma<<<288, 256, 0, stream>>>(cat, wcatA, b_cat, ybuf);
  for (int l = 0; l < 3; ++l) {
    conv1gdn_mfma<<<288, 256, 0, stream>>>(ybuf, w1A + l * 36864, gA + l * 4096,
                                           rb_beta + l * 64, hbuf);
    if (l < 2)
      conv2_mfma<false><<<288, 256, 0, stream>>>(hbuf, w2A + l * 36864, cat, ybuf, out);
    else
      conv2_mfma<true><<<288, 256, 0, stream>>>(hbuf, w2A + l * 36864, cat, ybuf, out);
  }
}

// Round 3
// 422.099 us; speedup vs baseline: 5.0004x; 2.7945x over previous
//
#include <hip/hip_runtime.h>

typedef __attribute__((ext_vector_type(8))) __bf16 bf16x8;
typedef __attribute__((ext_vector_type(4))) __bf16 bf16x4;
typedef __attribute__((ext_vector_type(16))) float f32x16;
typedef __attribute__((ext_vector_type(4))) float f32x4;

#define HH 192
#define WW 192
#define HW 36864
#define HW1 36100
#define PIX 73728

#define COLSTRIDE 144             // bytes per staged col: 64 bf16 = 128B + 16B pad
#define ROWPITCH (66 * COLSTRIDE) // 9504
#define GDNPITCH 144
#define TREG 8704                 // per-wave transpose region: 32 cols x 68 floats x 4B
#define SMEM_BYTES 57024          // 6*ROWPITCH

__device__ inline f32x16 mfma32(bf16x8 a, bf16x8 b, f32x16 c) {
  return __builtin_amdgcn_mfma_f32_32x32x16_bf16(a, b, c, 0, 0, 0);
}

__device__ inline f32x16 zero16() {
  f32x16 z;
#pragma unroll
  for (int e = 0; e < 16; ++e) z[e] = 0.f;
  return z;
}

// ---------------- weight prep: MFMA A-fragment layouts ----------------
// per (n, kc[, ot]) a 512-elem block: elem(lane,j) = W[o=ot*32+(lane&31)][c=kc*16+(lane>>5)*8+j]
__global__ __launch_bounds__(256) void prep_weights(
    const float* __restrict__ wp, const float* __restrict__ bp,
    const float* __restrict__ wdc, const float* __restrict__ wcat,
    const float* __restrict__ w1, const float* __restrict__ w2,
    const float* __restrict__ gamma,
    __bf16* __restrict__ wpA, __bf16* __restrict__ wdcA,
    __bf16* __restrict__ wcatA, __bf16* __restrict__ w1A,
    __bf16* __restrict__ w2A, __bf16* __restrict__ gA,
    float* __restrict__ bpad) {
  int i = blockIdx.x * 256 + threadIdx.x;
  if (i < 18432) {  // wpA: M=32 (o<18 valid), Cin=64, KC=4, 9 taps
    int j = i & 7, lane = (i >> 3) & 63, kc = (i >> 9) & 3, n = i >> 11;
    int o = lane & 31, c = kc * 16 + ((lane >> 5) << 3) + j;
    wpA[i] = (o < 18) ? (__bf16)wp[(o * 64 + c) * 9 + n] : (__bf16)0.f;
    return;
  }
  i -= 18432;
  if (i < 36864) {  // wdcA: Cin=64, KC=4
    int j = i & 7, lane = (i >> 3) & 63, ot = (i >> 9) & 1, kc = (i >> 10) & 3, n = i >> 12;
    int o = ot * 32 + (lane & 31), c = kc * 16 + ((lane >> 5) << 3) + j;
    wdcA[i] = (__bf16)wdc[(o * 64 + c) * 9 + n];
    return;
  }
  i -= 36864;
  if (i < 73728) {  // wcatA: Cin=128, KC=8
    int d = i, j = d & 7; d >>= 3; int lane = d & 63; d >>= 6; int ot = d & 1; d >>= 1;
    int kc = d & 7; int n = d >> 3;
    int o = ot * 32 + (lane & 31), c = kc * 16 + ((lane >> 5) << 3) + j;
    wcatA[i] = (__bf16)wcat[(o * 128 + c) * 9 + n];
    return;
  }
  i -= 73728;
  if (i < 110592) {  // w1A
    int l = i / 36864, di = i % 36864, d = di;
    int j = d & 7; d >>= 3; int lane = d & 63; d >>= 6; int ot = d & 1; d >>= 1;
    int kc = d & 3; int n = d >> 2;
    int o = ot * 32 + (lane & 31), c = kc * 16 + ((lane >> 5) << 3) + j;
    w1A[l * 36864 + di] = (__bf16)w1[l * 36864 + (o * 64 + c) * 9 + n];
    return;
  }
  i -= 110592;
  if (i < 110592) {  // w2A
    int l = i / 36864, di = i % 36864, d = di;
    int j = d & 7; d >>= 3; int lane = d & 63; d >>= 6; int ot = d & 1; d >>= 1;
    int kc = d & 3; int n = d >> 2;
    int o = ot * 32 + (lane & 31), c = kc * 16 + ((lane >> 5) << 3) + j;
    w2A[l * 36864 + di] = (__bf16)w2[l * 36864 + (o * 64 + c) * 9 + n];
    return;
  }
  i -= 110592;
  if (i < 12288) {  // gA
    int l = i / 4096, di = i % 4096, d = di;
    int j = d & 7; d >>= 3; int lane = d & 63; d >>= 6; int ot = d & 1; d >>= 1;
    int kc = d & 3;
    int o = ot * 32 + (lane & 31), c = kc * 16 + ((lane >> 5) << 3) + j;
    gA[l * 4096 + di] = (__bf16)gamma[l * 4096 + o * 64 + c];
    return;
  }
  i -= 12288;
  if (i < 20) bpad[i] = (i < 18) ? bp[i] : 0.f;
}

// ---------------- NCHW fp32 -> NHWC bf16 transpose (f_r and m_t) ----------------
__global__ __launch_bounds__(256) void to_nhwc_bf16(
    const float* __restrict__ fr, const float* __restrict__ mt,
    __bf16* __restrict__ frn, __bf16* __restrict__ mtn) {
  __shared__ __align__(16) __bf16 tile[64 * 72];
  int tensor = blockIdx.x / 1152, rem = blockIdx.x % 1152;
  int b = rem / 576, p0 = (rem % 576) * 64;
  const float* src = (tensor ? mt : fr) + (size_t)b * 64 * HW;
  __bf16* dst = (tensor ? mtn : frn) + (size_t)b * HW * 64;
  int tid = threadIdx.x, c = tid >> 2, q0 = (tid & 3) * 16;
  const float* sp = src + (size_t)c * HW + p0 + q0;
#pragma unroll
  for (int qq = 0; qq < 4; ++qq) {
    f32x4 v = *(const f32x4*)(sp + qq * 4);
#pragma unroll
    for (int e = 0; e < 4; ++e) tile[(q0 + qq * 4 + e) * 72 + c] = (__bf16)v[e];
  }
  __syncthreads();
  int px = tid >> 2, c0 = (tid & 3) * 16;
  bf16x8 a = *(const bf16x8*)(&tile[px * 72 + c0]);
  bf16x8 b8 = *(const bf16x8*)(&tile[px * 72 + c0 + 8]);
  __bf16* dp = dst + (size_t)(p0 + px) * 64 + c0;
  *(bf16x8*)dp = a;
  *(bf16x8*)(dp + 8) = b8;
}

// ---------------- staging helpers ----------------
__device__ inline void stage_f32(const float* __restrict__ src, int C, int cbase,
                                 int srcH, int srcW, int row0, int col0,
                                 unsigned char* lds) {
  for (int i = threadIdx.x; i < 6 * 66 * 16; i += 256) {
    int r = i / 1056, rem = i - r * 1056, j = rem >> 4, q = rem & 15;
    int gr = row0 + r, gc = col0 + j;
    f32x4 v = {0.f, 0.f, 0.f, 0.f};
    if (gr >= 0 && gr < srcH && gc >= 0 && gc < srcW)
      v = *(const f32x4*)(src + ((size_t)gr * srcW + gc) * C + cbase + q * 4);
    bf16x4 o;
#pragma unroll
    for (int e = 0; e < 4; ++e) o[e] = (__bf16)v[e];
    *(bf16x4*)(lds + r * ROWPITCH + j * COLSTRIDE + q * 8) = o;
  }
}

__device__ inline void stage_bf16(const __bf16* __restrict__ src,
                                  int srcH, int srcW, int row0, int col0,
                                  unsigned char* lds) {
  for (int i = threadIdx.x; i < 6 * 66 * 8; i += 256) {
    int r = i / 528, rem = i - r * 528, j = rem >> 3, u = rem & 7;
    int gr = row0 + r, gc = col0 + j;
    bf16x8 v;
#pragma unroll
    for (int e = 0; e < 8; ++e) v[e] = (__bf16)0.f;
    if (gr >= 0 && gr < srcH && gc >= 0 && gc < srcW)
      v = *(const bf16x8*)(src + ((size_t)gr * srcW + gc) * 64 + u * 8);
    *(bf16x8*)(lds + r * ROWPITCH + j * COLSTRIDE + u * 16) = v;
  }
}

// ---------------- MFMA K-loop (shared spatial-tile variant) ----------------
template <int KC, int KOFFA>
__device__ inline void kloop(const __bf16* __restrict__ wA,
                             const unsigned char* __restrict__ lds, int wp,
                             f32x16 acc[2][2]) {
  const int lane = threadIdx.x & 63;
  const int m = lane & 31;
  const int kh8 = (lane >> 5) << 3;
  const __bf16* aB = wA + lane * 8;
  const unsigned char* bB = lds + wp * ROWPITCH + m * COLSTRIDE + kh8 * 2;
#pragma unroll
  for (int n = 0; n < 9; ++n) {
    const int kh = n / 3, kw = n % 3;
#pragma unroll
    for (int kc = 0; kc < 4; ++kc) {
      bf16x8 a0 = *(const bf16x8*)(aB + ((n * KC + KOFFA + kc) * 2 + 0) * 512);
      bf16x8 a1 = *(const bf16x8*)(aB + ((n * KC + KOFFA + kc) * 2 + 1) * 512);
      const unsigned char* bp = bB + kh * ROWPITCH + kw * COLSTRIDE + kc * 32;
      bf16x8 b0 = *(const bf16x8*)(bp);
      bf16x8 b1 = *(const bf16x8*)(bp + 32 * COLSTRIDE);
      acc[0][0] = mfma32(a0, b0, acc[0][0]);
      acc[0][1] = mfma32(a0, b1, acc[0][1]);
      acc[1][0] = mfma32(a1, b0, acc[1][0]);
      acc[1][1] = mfma32(a1, b1, acc[1][1]);
    }
  }
}

// ---------------- epilogue helpers ----------------
__device__ inline void acchalf_to_lds(const f32x16 acc[2][2], int pt, unsigned char* reg) {
  int lane = threadIdx.x & 63;
  int colb = lane & 31, half = lane >> 5;
#pragma unroll
  for (int ot = 0; ot < 2; ++ot)
#pragma unroll
    for (int g = 0; g < 4; ++g) {
      int o = ot * 32 + half * 4 + g * 8;
      f32x4 v;
      v[0] = acc[ot][pt][g * 4 + 0]; v[1] = acc[ot][pt][g * 4 + 1];
      v[2] = acc[ot][pt][g * 4 + 2]; v[3] = acc[ot][pt][g * 4 + 3];
      *(f32x4*)(reg + (colb * 68 + o) * 4) = v;
    }
}

__device__ inline void read_half(const unsigned char* reg, f32x4 v[8]) {
  int lane = threadIdx.x & 63;
  int col = lane & 31, ch = (lane >> 5) * 32;
#pragma unroll
  for (int q = 0; q < 8; ++q)
    v[q] = *(const f32x4*)(reg + (col * 68 + ch + q * 4) * 4);
}

// ---------------- pconv MFMA: m_t (NHWC bf16) -> off20 NHWC [pix][20] fp32 ----------------
__global__ __launch_bounds__(256, 1) void pconv_mfma(
    const __bf16* __restrict__ mtn, const __bf16* __restrict__ wpA,
    const float* __restrict__ bpad, float* __restrict__ off20) {
  __shared__ __align__(16) unsigned char smem[SMEM_BYTES];
  int b = blockIdx.x / 144, r = blockIdx.x % 144, rt = r / 3, ct = r % 3;
  int h0 = rt * 4, w0 = ct * 64;
  int wid = threadIdx.x >> 6, lane = threadIdx.x & 63;
  int colb = lane & 31, half = lane >> 5, kh8 = half << 3;
  stage_bf16(mtn + (size_t)b * HW * 64, 192, 192, h0 - 1, w0 - 1, smem);
  __syncthreads();
  f32x16 acc[2];
  acc[0] = zero16(); acc[1] = zero16();
  {
    const __bf16* aB = wpA + lane * 8;
    const unsigned char* bB = smem + wid * ROWPITCH + colb * COLSTRIDE + kh8 * 2;
#pragma unroll
    for (int n = 0; n < 9; ++n) {
      const int kh = n / 3, kw = n % 3;
#pragma unroll
      for (int kc = 0; kc < 4; ++kc) {
        bf16x8 a = *(const bf16x8*)(aB + (n * 4 + kc) * 512);
        const unsigned char* bp = bB + kh * ROWPITCH + kw * COLSTRIDE + kc * 32;
        bf16x8 b0 = *(const bf16x8*)(bp);
        bf16x8 b1 = *(const bf16x8*)(bp + 32 * COLSTRIDE);
        acc[0] = mfma32(a, b0, acc[0]);
        acc[1] = mfma32(a, b1, acc[1]);
      }
    }
  }
  __syncthreads();
  unsigned char* reg = smem + wid * 9216;
#pragma unroll
  for (int pt = 0; pt < 2; ++pt)
#pragma unroll
    for (int g = 0; g < 4; ++g) {
      int o = half * 4 + g * 8;
      f32x4 v;
      v[0] = acc[pt][g * 4 + 0]; v[1] = acc[pt][g * 4 + 1];
      v[2] = acc[pt][g * 4 + 2]; v[3] = acc[pt][g * 4 + 3];
      *(f32x4*)(reg + ((pt * 32 + colb) * 36 + o) * 4) = v;
    }
  __builtin_amdgcn_s_waitcnt(0);
  size_t pix = (size_t)b * HW + (size_t)(h0 + wid) * 192 + w0 + lane;
#pragma unroll
  for (int q = 0; q < 5; ++q) {
    f32x4 v = *(const f32x4*)(reg + (lane * 36 + q * 4) * 4);
    v += *(const f32x4*)(bpad + q * 4);
    *(f32x4*)(off20 + pix * 20 + q * 4) = v;
  }
}

// ---------------- deformable conv MFMA: gathers from frn (NHWC bf16) ----------------
__global__ __launch_bounds__(128, 2) void deform_mfma(
    const __bf16* __restrict__ frn, const float* __restrict__ off20,
    const __bf16* __restrict__ wdcA, float* __restrict__ xlow) {
  __shared__ __align__(16) unsigned char smem[2 * 18432];
  int b = blockIdx.x / 288, r = blockIdx.x % 288, rt = r / 3, ct = r % 3;
  int h0 = rt * 2, w0 = ct * 64;
  int wid = threadIdx.x >> 6, lane = threadIdx.x & 63;
  int h = h0 + wid, w = w0 + lane;
  const __bf16* xb = frn + (size_t)b * HW * 64;
  size_t pixl = (size_t)b * HW + (size_t)h * 192 + w0 + lane;
  f32x4 ofv[5];
#pragma unroll
  for (int q = 0; q < 5; ++q) ofv[q] = *(const f32x4*)(off20 + pixl * 20 + q * 4);
  f32x16 acc[2][2];
  acc[0][0] = zero16(); acc[0][1] = zero16(); acc[1][0] = zero16(); acc[1][1] = zero16();
  const __bf16* aB = wdcA + lane * 8;
  const int m = lane & 31, kh8 = (lane >> 5) << 3;
#pragma unroll
  for (int n = 0; n < 9; ++n) {
    unsigned char* buf = smem + wid * 18432 + (n & 1) * 9216;
    float offr = ofv[n >> 2][n & 3];
    float offc = ofv[(n + 9) >> 2][(n + 9) & 3];
    float pr = (float)(h + 1 + n / 3 - 1) + offr;
    float pc = (float)(w + 1 + n % 3 - 1) + offc;
    float prc = fminf(fmaxf(pr, 0.f), 193.f);
    float pcc = fminf(fmaxf(pc, 0.f), 193.f);
    float f0r = floorf(pr), f0c = floorf(pc);
    int qr0 = (int)fminf(fmaxf(f0r, 0.f), 193.f);
    int qc0 = (int)fminf(fmaxf(f0c, 0.f), 193.f);
    int qr1 = (int)fminf(fmaxf(f0r + 1.f, 0.f), 193.f);
    int qc1 = (int)fminf(fmaxf(f0c + 1.f, 0.f), 193.f);
    float dr0 = 1.f + ((float)qr0 - prc);
    float dr1 = 1.f - ((float)qr1 - prc);
    float dc0 = 1.f + ((float)qc0 - pcc);
    float dc1 = 1.f - ((float)qc1 - pcc);
    int o0, o1, o2, o3; float g0, g1, g2, g3;
    { bool v = (qr0 >= 1 && qr0 <= 192 && qc0 >= 1 && qc0 <= 192);
      o0 = min(max(qr0-1,0),191)*WW + min(max(qc0-1,0),191); g0 = v ? dr0*dc0 : 0.f; }
    { bool v = (qr1 >= 1 && qr1 <= 192 && qc1 >= 1 && qc1 <= 192);
      o1 = min(max(qr1-1,0),191)*WW + min(max(qc1-1,0),191); g1 = v ? dr1*dc1 : 0.f; }
    { bool v = (qr0 >= 1 && qr0 <= 192 && qc1 >= 1 && qc1 <= 192);
      o2 = min(max(qr0-1,0),191)*WW + min(max(qc1-1,0),191); g2 = v ? dr0*dc1 : 0.f; }
    { bool v = (qr1 >= 1 && qr1 <= 192 && qc0 >= 1 && qc0 <= 192);
      o3 = min(max(qr1-1,0),191)*WW + min(max(qc0-1,0),191); g3 = v ? dr1*dc0 : 0.f; }
    const __bf16* p0 = xb + (size_t)o0 * 64;
    const __bf16* p1 = xb + (size_t)o1 * 64;
    const __bf16* p2 = xb + (size_t)o2 * 64;
    const __bf16* p3 = xb + (size_t)o3 * 64;
#pragma unroll
    for (int u = 0; u < 8; ++u) {
      bf16x8 c0 = *(const bf16x8*)(p0 + u * 8);
      bf16x8 c1 = *(const bf16x8*)(p1 + u * 8);
      bf16x8 c2 = *(const bf16x8*)(p2 + u * 8);
      bf16x8 c3 = *(const bf16x8*)(p3 + u * 8);
      bf16x8 ov;
#pragma unroll
      for (int e = 0; e < 8; ++e) {
        float f = g0 * (float)c0[e] + g1 * (float)c1[e] + g2 * (float)c2[e] + g3 * (float)c3[e];
        ov[e] = (__bf16)f;
      }
      *(bf16x8*)(buf + lane * 144 + u * 16) = ov;
    }
    const unsigned char* bB = buf + m * 144 + kh8 * 2;
#pragma unroll
    for (int kc = 0; kc < 4; ++kc) {
      bf16x8 a0 = *(const bf16x8*)(aB + ((n * 4 + kc) * 2 + 0) * 512);
      bf16x8 a1 = *(const bf16x8*)(aB + ((n * 4 + kc) * 2 + 1) * 512);
      bf16x8 b0 = *(const bf16x8*)(bB + kc * 32);
      bf16x8 b1 = *(const bf16x8*)(bB + 32 * 144 + kc * 32);
      acc[0][0] = mfma32(a0, b0, acc[0][0]);
      acc[0][1] = mfma32(a0, b1, acc[0][1]);
      acc[1][0] = mfma32(a1, b0, acc[1][0]);
      acc[1][1] = mfma32(a1, b1, acc[1][1]);
    }
  }
  unsigned char* reg = smem + wid * 18432;
  int col = lane & 31, ch = (lane >> 5) * 32;
  float* dsty = xlow + ((size_t)b * HW + (size_t)h * 192 + w0) * 64;
#pragma unroll
  for (int pt = 0; pt < 2; ++pt) {
    acchalf_to_lds(acc, pt, reg);
    __builtin_amdgcn_s_waitcnt(0);
    f32x4 v[8];
    read_half(reg, v);
    float* dp = dsty + (size_t)(pt * 32 + col) * 64 + ch;
#pragma unroll
    for (int q = 0; q < 8; ++q) *(f32x4*)(dp + q * 4) = v[q];
  }
}

// ---------------- convcat: chunk1 = xlow (fp32 NHWC), chunk2 = frn (bf16 NHWC) ----------------
__global__ __launch_bounds__(256, 1) void convcat_mfma(
    const float* __restrict__ xlow, const __bf16* __restrict__ frn,
    const __bf16* __restrict__ wA, const float* __restrict__ bias,
    float* __restrict__ y) {
  __shared__ __align__(16) unsigned char smem[SMEM_BYTES];
  int b = blockIdx.x / 144, r = blockIdx.x % 144, rt = r / 3, ct = r % 3;
  int h0 = rt * 4, w0 = ct * 64;
  int wid = threadIdx.x >> 6, lane = threadIdx.x & 63;
  f32x16 acc[2][2];
  acc[0][0] = zero16(); acc[0][1] = zero16(); acc[1][0] = zero16(); acc[1][1] = zero16();
  stage_f32(xlow + (size_t)b * HW * 64, 64, 0, 192, 192, h0 - 1, w0 - 1, smem);
  __syncthreads();
  kloop<8, 0>(wA, smem, wid, acc);
  __syncthreads();
  stage_bf16(frn + (size_t)b * HW * 64, 192, 192, h0 - 1, w0 - 1, smem);
  __syncthreads();
  kloop<8, 4>(wA, smem, wid, acc);
  __syncthreads();
  unsigned char* reg = smem + wid * TREG;
  float* dsty = y + ((size_t)b * HW + (size_t)(h0 + wid) * 192 + w0) * 64;
  int col = lane & 31, ch = (lane >> 5) * 32;
#pragma unroll
  for (int pt = 0; pt < 2; ++pt) {
    acchalf_to_lds(acc, pt, reg);
    __builtin_amdgcn_s_waitcnt(0);
    f32x4 v[8];
    read_half(reg, v);
    float* dp = dsty + (size_t)(pt * 32 + col) * 64 + ch;
#pragma unroll
    for (int q = 0; q < 8; ++q) {
      f32x4 bv = *(const f32x4*)(bias + ch + q * 4);
      v[q] += bv;
      *(f32x4*)(dp + q * 4) = v[q];
    }
  }
}

// ---------------- conv1 + GDN + CELU ----------------
__global__ __launch_bounds__(256, 1) void conv1gdn_mfma(
    const float* __restrict__ y, const __bf16* __restrict__ w1A,
    const __bf16* __restrict__ gA, const float* __restrict__ beta,
    __bf16* __restrict__ hbuf) {
  __shared__ __align__(16) unsigned char smem[SMEM_BYTES];
  int b = blockIdx.x / 144, r = blockIdx.x % 144, rt = r / 3, ct = r % 3;
  int h0 = rt * 4, w0 = ct * 64;
  int wid = threadIdx.x >> 6, lane = threadIdx.x & 63;
  int colb = lane & 31, half = lane >> 5;
  const int kh8 = half << 3;
  f32x16 acc[2][2];
  acc[0][0] = zero16(); acc[0][1] = zero16(); acc[1][0] = zero16(); acc[1][1] = zero16();
  stage_f32(y + (size_t)b * HW * 64, 64, 0, 192, 192, h0, w0, smem);
  __syncthreads();
  kloop<4, 0>(w1A, smem, wid, acc);
  __syncthreads();
#pragma unroll
  for (int ot = 0; ot < 2; ++ot)
#pragma unroll
    for (int pt = 0; pt < 2; ++pt)
#pragma unroll
      for (int g = 0; g < 4; ++g) {
        int o = ot * 32 + half * 4 + g * 8;
        int p = wid * 64 + pt * 32 + colb;
        bf16x4 s;
#pragma unroll
        for (int e = 0; e < 4; ++e) {
          float x = acc[ot][pt][g * 4 + e];
          s[e] = (__bf16)(x * x);
        }
        *(bf16x4*)(smem + p * GDNPITCH + o * 2) = s;
      }
  __syncthreads();
  f32x16 nacc[2][2];
  nacc[0][0] = zero16(); nacc[0][1] = zero16(); nacc[1][0] = zero16(); nacc[1][1] = zero16();
  {
    const __bf16* gaB = gA + lane * 8;
    const unsigned char* gb = smem + (wid * 64 + colb) * GDNPITCH + kh8 * 2;
#pragma unroll
    for (int kc = 0; kc < 4; ++kc) {
      bf16x8 a0 = *(const bf16x8*)(gaB + (kc * 2 + 0) * 512);
      bf16x8 a1 = *(const bf16x8*)(gaB + (kc * 2 + 1) * 512);
      bf16x8 b0 = *(const bf16x8*)(gb + kc * 32);
      bf16x8 b1 = *(const bf16x8*)(gb + 32 * GDNPITCH + kc * 32);
      nacc[0][0] = mfma32(a0, b0, nacc[0][0]);
      nacc[0][1] = mfma32(a0, b1, nacc[0][1]);
      nacc[1][0] = mfma32(a1, b0, nacc[1][0]);
      nacc[1][1] = mfma32(a1, b1, nacc[1][1]);
    }
  }
#pragma unroll
  for (int ot = 0; ot < 2; ++ot)
#pragma unroll
    for (int g = 0; g < 4; ++g) {
      f32x4 bet = *(const f32x4*)(beta + ot * 32 + half * 4 + g * 8);
#pragma unroll
      for (int pt = 0; pt < 2; ++pt)
#pragma unroll
        for (int e = 0; e < 4; ++e) {
          float nv = bet[e] + nacc[ot][pt][g * 4 + e];
          float hv = acc[ot][pt][g * 4 + e] * rsqrtf(nv);
          hv = hv > 0.f ? hv : expf(hv) - 1.f;
          acc[ot][pt][g * 4 + e] = hv;
        }
    }
  __syncthreads();
  unsigned char* reg = smem + wid * TREG;
  int hr = h0 + wid;
  bool rowok = hr < 190;
  int ch = half * 32;
#pragma unroll
  for (int pt = 0; pt < 2; ++pt) {
    acchalf_to_lds(acc, pt, reg);
    __builtin_amdgcn_s_waitcnt(0);
    f32x4 v[8];
    read_half(reg, v);
    int wcol = w0 + pt * 32 + colb;
    if (rowok && wcol < 190) {
      __bf16* dp = hbuf + ((size_t)b * HW1 + (size_t)hr * 190 + wcol) * 64 + ch;
#pragma unroll
      for (int q = 0; q < 8; ++q) {
        bf16x4 o;
#pragma unroll
        for (int e = 0; e < 4; ++e) o[e] = (__bf16)v[q][e];
        *(bf16x4*)(dp + q * 4) = o;
      }
    }
  }
}

// ---------------- conv2 (pad 2) + residual; LAST adds x and writes NCHW out ----------------
template <bool LAST>
__global__ __launch_bounds__(256, 1) void conv2_mfma(
    const __bf16* __restrict__ hbuf, const __bf16* __restrict__ w2A,
    const float* __restrict__ xlow, float* __restrict__ y,
    float* __restrict__ out) {
  __shared__ __align__(16) unsigned char smem[SMEM_BYTES];
  int b = blockIdx.x / 144, r = blockIdx.x % 144, rt = r / 3, ct = r % 3;
  int h0 = rt * 4, w0 = ct * 64;
  int wid = threadIdx.x >> 6, lane = threadIdx.x & 63;
  f32x16 acc[2][2];
  acc[0][0] = zero16(); acc[0][1] = zero16(); acc[1][0] = zero16(); acc[1][1] = zero16();
  stage_bf16(hbuf + (size_t)b * HW1 * 64, 190, 190, h0 - 2, w0 - 2, smem);
  __syncthreads();
  kloop<4, 0>(w2A, smem, wid, acc);
  __syncthreads();
  unsigned char* reg = smem + wid * TREG;
  int col = lane & 31, ch = (lane >> 5) * 32;
  size_t pixbase = (size_t)b * HW + (size_t)(h0 + wid) * 192 + w0;
#pragma unroll
  for (int pt = 0; pt < 2; ++pt) {
    acchalf_to_lds(acc, pt, reg);
    __builtin_amdgcn_s_waitcnt(0);
    f32x4 v[8];
    read_half(reg, v);
    size_t pix = pixbase + pt * 32 + col;
    float* yp = y + pix * 64 + ch;
#pragma unroll
    for (int q = 0; q < 8; ++q) v[q] += *(const f32x4*)(yp + q * 4);
    if (!LAST) {
#pragma unroll
      for (int q = 0; q < 8; ++q) *(f32x4*)(yp + q * 4) = v[q];
    } else {
      const float* xp = xlow + pix * 64 + ch;
#pragma unroll
      for (int q = 0; q < 8; ++q) v[q] += *(const f32x4*)(xp + q * 4);
#pragma unroll
      for (int q = 0; q < 8; ++q)
        *(f32x4*)(reg + (col * 68 + ch + q * 4) * 4) = v[q];
      __builtin_amdgcn_s_waitcnt(0);
      int o = lane;
      float* op = out + ((size_t)b * 64 + o) * HW + (size_t)(h0 + wid) * 192 + w0 + pt * 32;
#pragma unroll
      for (int q = 0; q < 8; ++q) {
        f32x4 s;
#pragma unroll
        for (int e = 0; e < 4; ++e)
          s[e] = *(const float*)(reg + ((q * 4 + e) * 68 + o) * 4);
        *(f32x4*)(op + q * 4) = s;
      }
    }
  }
}

extern "C" void kernel_launch(void* const* d_in, const int* in_sizes, int n_in,
                              void* d_out, int out_size, void* d_ws, size_t ws_size,
                              hipStream_t stream) {
  const float* f_r      = (const float*)d_in[0];
  const float* m_t      = (const float*)d_in[1];
  const float* w_pconv  = (const float*)d_in[2];
  const float* b_pconv  = (const float*)d_in[3];
  const float* w_dc     = (const float*)d_in[4];
  const float* w_cat    = (const float*)d_in[5];
  const float* b_cat    = (const float*)d_in[6];
  const float* rb_w1    = (const float*)d_in[7];
  const float* rb_w2    = (const float*)d_in[8];
  const float* rb_beta  = (const float*)d_in[9];
  const float* rb_gamma = (const float*)d_in[10];
  float* out = (float*)d_out;

  float* ws = (float*)d_ws;
  float*  xlow  = ws;                         // [2][HW][64] f32 (deform out = residual x)
  float*  ybuf  = xlow + 4718592;             // [2][HW][64] f32
  float*  off20 = ybuf + 4718592;             // [2][HW][20] f32
  __bf16* frn   = (__bf16*)(off20 + 1474560); // [2][HW][64] bf16
  __bf16* mtn   = (__bf16*)(off20 + 1474560 + 2359296); // bf16; aliased with hbuf
  __bf16* hbuf  = mtn;                        // mtn dead after pconv; hbuf written later
  float*  wbase = off20 + 1474560 + 2359296 + 2359296;
  __bf16* wpA   = (__bf16*)wbase;             // 18432 bf16
  __bf16* wdcA  = (__bf16*)(wbase + 9216);    // 36864 bf16
  __bf16* wcatA = (__bf16*)(wbase + 27648);   // 73728 bf16
  __bf16* w1A   = (__bf16*)(wbase + 64512);   // 110592 bf16
  __bf16* w2A   = (__bf16*)(wbase + 119808);  // 110592 bf16
  __bf16* gA    = (__bf16*)(wbase + 175104);  // 12288 bf16
  float*  bpad  = wbase + 181248;             // 20 f32

  prep_weights<<<1417, 256, 0, stream>>>(w_pconv, b_pconv, w_dc, w_cat, rb_w1, rb_w2,
                                         rb_gamma, wpA, wdcA, wcatA, w1A, w2A, gA, bpad);
  to_nhwc_bf16<<<2304, 256, 0, stream>>>(f_r, m_t, frn, mtn);
  pconv_mfma<<<288, 256, 0, stream>>>(mtn, wpA, bpad, off20);
  deform_mfma<<<576, 128, 0, stream>>>(frn, off20, wdcA, xlow);
  convcat_mfma<<<288, 256, 0, stream>>>(xlow, frn, wcatA, b_cat, ybuf);
  for (int l = 0; l < 3; ++l) {
    conv1gdn_mfma<<<288, 256, 0, stream>>>(ybuf, w1A + l * 36864, gA + l * 4096,
                                           rb_beta + l * 64, hbuf);
    if (l < 2)
      conv2_mfma<false><<<288, 256, 0, stream>>>(hbuf, w2A + l * 36864, xlow, ybuf, out);
    else
      conv2_mfma<true><<<288, 256, 0, stream>>>(hbuf, w2A + l * 36864, xlow, ybuf, out);
  }
}

// Round 4
// 369.732 us; speedup vs baseline: 5.7086x; 1.1416x over previous
//
#include <hip/hip_runtime.h>

typedef __attribute__((ext_vector_type(8))) __bf16 bf16x8;
typedef __attribute__((ext_vector_type(4))) __bf16 bf16x4;
typedef __attribute__((ext_vector_type(16))) float f32x16;
typedef __attribute__((ext_vector_type(4))) float f32x4;

#define HH 192
#define WW 192
#define HW 36864
#define HW1 36100
#define PIX 73728

#define COLSTRIDE 144             // bytes per staged col: 64 bf16 = 128B + 16B pad
#define ROWPITCH (66 * COLSTRIDE) // 9504
#define GDNPITCH 144
#define TREG 8704                 // per-wave transpose region: 32 cols x 68 floats x 4B
#define SMEM_BYTES 57024          // 6*ROWPITCH

__device__ inline f32x16 mfma32(bf16x8 a, bf16x8 b, f32x16 c) {
  return __builtin_amdgcn_mfma_f32_32x32x16_bf16(a, b, c, 0, 0, 0);
}

__device__ inline f32x16 zero16() {
  f32x16 z;
#pragma unroll
  for (int e = 0; e < 16; ++e) z[e] = 0.f;
  return z;
}

// ---------------- weight prep: MFMA A-fragment layouts ----------------
// per (n, kc[, ot]) a 512-elem block: elem(lane,j) = W[o=ot*32+(lane&31)][c=kc*16+(lane>>5)*8+j]
__global__ __launch_bounds__(256) void prep_weights(
    const float* __restrict__ wp, const float* __restrict__ bp,
    const float* __restrict__ wdc, const float* __restrict__ wcat,
    const float* __restrict__ w1, const float* __restrict__ w2,
    const float* __restrict__ gamma,
    __bf16* __restrict__ wpA, __bf16* __restrict__ wdcA,
    __bf16* __restrict__ wcatA, __bf16* __restrict__ w1A,
    __bf16* __restrict__ w2A, __bf16* __restrict__ gA,
    float* __restrict__ bpad) {
  int i = blockIdx.x * 256 + threadIdx.x;
  if (i < 18432) {  // wpA: M=32 (o<18 valid), Cin=64, KC=4, 9 taps
    int j = i & 7, lane = (i >> 3) & 63, kc = (i >> 9) & 3, n = i >> 11;
    int o = lane & 31, c = kc * 16 + ((lane >> 5) << 3) + j;
    wpA[i] = (o < 18) ? (__bf16)wp[(o * 64 + c) * 9 + n] : (__bf16)0.f;
    return;
  }
  i -= 18432;
  if (i < 36864) {  // wdcA: Cin=64, KC=4
    int j = i & 7, lane = (i >> 3) & 63, ot = (i >> 9) & 1, kc = (i >> 10) & 3, n = i >> 12;
    int o = ot * 32 + (lane & 31), c = kc * 16 + ((lane >> 5) << 3) + j;
    wdcA[i] = (__bf16)wdc[(o * 64 + c) * 9 + n];
    return;
  }
  i -= 36864;
  if (i < 73728) {  // wcatA: Cin=128, KC=8
    int d = i, j = d & 7; d >>= 3; int lane = d & 63; d >>= 6; int ot = d & 1; d >>= 1;
    int kc = d & 7; int n = d >> 3;
    int o = ot * 32 + (lane & 31), c = kc * 16 + ((lane >> 5) << 3) + j;
    wcatA[i] = (__bf16)wcat[(o * 128 + c) * 9 + n];
    return;
  }
  i -= 73728;
  if (i < 110592) {  // w1A
    int l = i / 36864, di = i % 36864, d = di;
    int j = d & 7; d >>= 3; int lane = d & 63; d >>= 6; int ot = d & 1; d >>= 1;
    int kc = d & 3; int n = d >> 2;
    int o = ot * 32 + (lane & 31), c = kc * 16 + ((lane >> 5) << 3) + j;
    w1A[l * 36864 + di] = (__bf16)w1[l * 36864 + (o * 64 + c) * 9 + n];
    return;
  }
  i -= 110592;
  if (i < 110592) {  // w2A
    int l = i / 36864, di = i % 36864, d = di;
    int j = d & 7; d >>= 3; int lane = d & 63; d >>= 6; int ot = d & 1; d >>= 1;
    int kc = d & 3; int n = d >> 2;
    int o = ot * 32 + (lane & 31), c = kc * 16 + ((lane >> 5) << 3) + j;
    w2A[l * 36864 + di] = (__bf16)w2[l * 36864 + (o * 64 + c) * 9 + n];
    return;
  }
  i -= 110592;
  if (i < 12288) {  // gA
    int l = i / 4096, di = i % 4096, d = di;
    int j = d & 7; d >>= 3; int lane = d & 63; d >>= 6; int ot = d & 1; d >>= 1;
    int kc = d & 3;
    int o = ot * 32 + (lane & 31), c = kc * 16 + ((lane >> 5) << 3) + j;
    gA[l * 4096 + di] = (__bf16)gamma[l * 4096 + o * 64 + c];
    return;
  }
  i -= 12288;
  if (i < 20) bpad[i] = (i < 18) ? bp[i] : 0.f;
}

// ---------------- NCHW fp32 -> NHWC bf16 transpose (f_r and m_t) ----------------
__global__ __launch_bounds__(256) void to_nhwc_bf16(
    const float* __restrict__ fr, const float* __restrict__ mt,
    __bf16* __restrict__ frn, __bf16* __restrict__ mtn) {
  __shared__ __align__(16) __bf16 tile[64 * 72];
  int tensor = blockIdx.x / 1152, rem = blockIdx.x % 1152;
  int b = rem / 576, p0 = (rem % 576) * 64;
  const float* src = (tensor ? mt : fr) + (size_t)b * 64 * HW;
  __bf16* dst = (tensor ? mtn : frn) + (size_t)b * HW * 64;
  int tid = threadIdx.x, c = tid >> 2, q0 = (tid & 3) * 16;
  const float* sp = src + (size_t)c * HW + p0 + q0;
#pragma unroll
  for (int qq = 0; qq < 4; ++qq) {
    f32x4 v = *(const f32x4*)(sp + qq * 4);
#pragma unroll
    for (int e = 0; e < 4; ++e) tile[(q0 + qq * 4 + e) * 72 + c] = (__bf16)v[e];
  }
  __syncthreads();
  int px = tid >> 2, c0 = (tid & 3) * 16;
  bf16x8 a = *(const bf16x8*)(&tile[px * 72 + c0]);
  bf16x8 b8 = *(const bf16x8*)(&tile[px * 72 + c0 + 8]);
  __bf16* dp = dst + (size_t)(p0 + px) * 64 + c0;
  *(bf16x8*)dp = a;
  *(bf16x8*)(dp + 8) = b8;
}

// ---------------- staging helpers ----------------
__device__ inline void stage_f32(const float* __restrict__ src, int C, int cbase,
                                 int srcH, int srcW, int row0, int col0,
                                 unsigned char* lds) {
  for (int i = threadIdx.x; i < 6 * 66 * 16; i += 256) {
    int r = i / 1056, rem = i - r * 1056, j = rem >> 4, q = rem & 15;
    int gr = row0 + r, gc = col0 + j;
    f32x4 v = {0.f, 0.f, 0.f, 0.f};
    if (gr >= 0 && gr < srcH && gc >= 0 && gc < srcW)
      v = *(const f32x4*)(src + ((size_t)gr * srcW + gc) * C + cbase + q * 4);
    bf16x4 o;
#pragma unroll
    for (int e = 0; e < 4; ++e) o[e] = (__bf16)v[e];
    *(bf16x4*)(lds + r * ROWPITCH + j * COLSTRIDE + q * 8) = o;
  }
}

__device__ inline void stage_bf16(const __bf16* __restrict__ src,
                                  int srcH, int srcW, int row0, int col0,
                                  unsigned char* lds) {
  for (int i = threadIdx.x; i < 6 * 66 * 8; i += 256) {
    int r = i / 528, rem = i - r * 528, j = rem >> 3, u = rem & 7;
    int gr = row0 + r, gc = col0 + j;
    bf16x8 v;
#pragma unroll
    for (int e = 0; e < 8; ++e) v[e] = (__bf16)0.f;
    if (gr >= 0 && gr < srcH && gc >= 0 && gc < srcW)
      v = *(const bf16x8*)(src + ((size_t)gr * srcW + gc) * 64 + u * 8);
    *(bf16x8*)(lds + r * ROWPITCH + j * COLSTRIDE + u * 16) = v;
  }
}

// ---------------- MFMA K-loop (shared spatial-tile variant) ----------------
template <int KC, int KOFFA>
__device__ inline void kloop(const __bf16* __restrict__ wA,
                             const unsigned char* __restrict__ lds, int wp,
                             f32x16 acc[2][2]) {
  const int lane = threadIdx.x & 63;
  const int m = lane & 31;
  const int kh8 = (lane >> 5) << 3;
  const __bf16* aB = wA + lane * 8;
  const unsigned char* bB = lds + wp * ROWPITCH + m * COLSTRIDE + kh8 * 2;
#pragma unroll
  for (int n = 0; n < 9; ++n) {
    const int kh = n / 3, kw = n % 3;
#pragma unroll
    for (int kc = 0; kc < 4; ++kc) {
      bf16x8 a0 = *(const bf16x8*)(aB + ((n * KC + KOFFA + kc) * 2 + 0) * 512);
      bf16x8 a1 = *(const bf16x8*)(aB + ((n * KC + KOFFA + kc) * 2 + 1) * 512);
      const unsigned char* bp = bB + kh * ROWPITCH + kw * COLSTRIDE + kc * 32;
      bf16x8 b0 = *(const bf16x8*)(bp);
      bf16x8 b1 = *(const bf16x8*)(bp + 32 * COLSTRIDE);
      acc[0][0] = mfma32(a0, b0, acc[0][0]);
      acc[0][1] = mfma32(a0, b1, acc[0][1]);
      acc[1][0] = mfma32(a1, b0, acc[1][0]);
      acc[1][1] = mfma32(a1, b1, acc[1][1]);
    }
  }
}

// ---------------- epilogue helpers ----------------
__device__ inline void acchalf_to_lds(const f32x16 acc[2][2], int pt, unsigned char* reg) {
  int lane = threadIdx.x & 63;
  int colb = lane & 31, half = lane >> 5;
#pragma unroll
  for (int ot = 0; ot < 2; ++ot)
#pragma unroll
    for (int g = 0; g < 4; ++g) {
      int o = ot * 32 + half * 4 + g * 8;
      f32x4 v;
      v[0] = acc[ot][pt][g * 4 + 0]; v[1] = acc[ot][pt][g * 4 + 1];
      v[2] = acc[ot][pt][g * 4 + 2]; v[3] = acc[ot][pt][g * 4 + 3];
      *(f32x4*)(reg + (colb * 68 + o) * 4) = v;
    }
}

__device__ inline void read_half(const unsigned char* reg, f32x4 v[8]) {
  int lane = threadIdx.x & 63;
  int col = lane & 31, ch = (lane >> 5) * 32;
#pragma unroll
  for (int q = 0; q < 8; ++q)
    v[q] = *(const f32x4*)(reg + (col * 68 + ch + q * 4) * 4);
}

// ---------------- pconv MFMA: m_t (NHWC bf16) -> off20 NHWC [pix][20] fp32 ----------------
__global__ __launch_bounds__(256, 1) void pconv_mfma(
    const __bf16* __restrict__ mtn, const __bf16* __restrict__ wpA,
    const float* __restrict__ bpad, float* __restrict__ off20) {
  __shared__ __align__(16) unsigned char smem[SMEM_BYTES];
  int b = blockIdx.x / 144, r = blockIdx.x % 144, rt = r / 3, ct = r % 3;
  int h0 = rt * 4, w0 = ct * 64;
  int wid = threadIdx.x >> 6, lane = threadIdx.x & 63;
  int colb = lane & 31, half = lane >> 5, kh8 = half << 3;
  stage_bf16(mtn + (size_t)b * HW * 64, 192, 192, h0 - 1, w0 - 1, smem);
  __syncthreads();
  f32x16 acc[2];
  acc[0] = zero16(); acc[1] = zero16();
  {
    const __bf16* aB = wpA + lane * 8;
    const unsigned char* bB = smem + wid * ROWPITCH + colb * COLSTRIDE + kh8 * 2;
#pragma unroll
    for (int n = 0; n < 9; ++n) {
      const int kh = n / 3, kw = n % 3;
#pragma unroll
      for (int kc = 0; kc < 4; ++kc) {
        bf16x8 a = *(const bf16x8*)(aB + (n * 4 + kc) * 512);
        const unsigned char* bp = bB + kh * ROWPITCH + kw * COLSTRIDE + kc * 32;
        bf16x8 b0 = *(const bf16x8*)(bp);
        bf16x8 b1 = *(const bf16x8*)(bp + 32 * COLSTRIDE);
        acc[0] = mfma32(a, b0, acc[0]);
        acc[1] = mfma32(a, b1, acc[1]);
      }
    }
  }
  __syncthreads();
  unsigned char* reg = smem + wid * 9216;
#pragma unroll
  for (int pt = 0; pt < 2; ++pt)
#pragma unroll
    for (int g = 0; g < 4; ++g) {
      int o = half * 4 + g * 8;
      f32x4 v;
      v[0] = acc[pt][g * 4 + 0]; v[1] = acc[pt][g * 4 + 1];
      v[2] = acc[pt][g * 4 + 2]; v[3] = acc[pt][g * 4 + 3];
      *(f32x4*)(reg + ((pt * 32 + colb) * 36 + o) * 4) = v;
    }
  __builtin_amdgcn_s_waitcnt(0);
  size_t pix = (size_t)b * HW + (size_t)(h0 + wid) * 192 + w0 + lane;
#pragma unroll
  for (int q = 0; q < 5; ++q) {
    f32x4 v = *(const f32x4*)(reg + (lane * 36 + q * 4) * 4);
    v += *(const f32x4*)(bpad + q * 4);
    *(f32x4*)(off20 + pix * 20 + q * 4) = v;
  }
}

// ---------------- deformable conv MFMA, coalesced gather ----------------
// block = 128 thr (2 waves), covers 1 row x 64 cols; wave handles 32 px (N=32).
// lane = (po=lane>>3, cg=lane&7): gathers 16B of channels for pixels po*4+i —
// 8 consecutive lanes read one contiguous 128B pixel row (16 lines/instr vs 64).
__global__ __launch_bounds__(128, 2) void deform_mfma(
    const __bf16* __restrict__ frn, const float* __restrict__ off20,
    const __bf16* __restrict__ wdcA, float* __restrict__ xlow) {
  __shared__ __align__(16) unsigned char smem[2 * 18432];
  int b = blockIdx.x / 576, r = blockIdx.x % 576;
  int h = r / 3, ct = r % 3;
  int w0 = ct * 64;
  int wid = threadIdx.x >> 6, lane = threadIdx.x & 63;
  int wcol0 = w0 + wid * 32;
  unsigned char* wbase = smem + wid * 18432;
  float* goL = (float*)wbase;       // [9 taps][32 px][8]: g0..g3, o0..o3(int)
  unsigned char* dbuf = wbase + 9216;
  const __bf16* xb = frn + (size_t)b * HW * 64;
  // ---- prologue: per-pixel per-tap bilinear params into LDS (lanes split taps by parity)
  {
    int px = lane & 31, par = lane >> 5;
    int w = wcol0 + px;
    size_t pixl = (size_t)b * HW + (size_t)h * 192 + w;
    const float* ofp = off20 + pixl * 20;
    for (int n = par; n < 9; n += 2) {
      float offr = ofp[n], offc = ofp[9 + n];
      float pr = (float)(h + 1 + n / 3 - 1) + offr;
      float pc = (float)(w + 1 + n % 3 - 1) + offc;
      float prc = fminf(fmaxf(pr, 0.f), 193.f);
      float pcc = fminf(fmaxf(pc, 0.f), 193.f);
      float f0r = floorf(pr), f0c = floorf(pc);
      int qr0 = (int)fminf(fmaxf(f0r, 0.f), 193.f);
      int qc0 = (int)fminf(fmaxf(f0c, 0.f), 193.f);
      int qr1 = (int)fminf(fmaxf(f0r + 1.f, 0.f), 193.f);
      int qc1 = (int)fminf(fmaxf(f0c + 1.f, 0.f), 193.f);
      float dr0 = 1.f + ((float)qr0 - prc);
      float dr1 = 1.f - ((float)qr1 - prc);
      float dc0 = 1.f + ((float)qc0 - pcc);
      float dc1 = 1.f - ((float)qc1 - pcc);
      int o0, o1, o2, o3; float g0, g1, g2, g3;
      { bool v = (qr0 >= 1 && qr0 <= 192 && qc0 >= 1 && qc0 <= 192);
        o0 = min(max(qr0-1,0),191)*WW + min(max(qc0-1,0),191); g0 = v ? dr0*dc0 : 0.f; }
      { bool v = (qr1 >= 1 && qr1 <= 192 && qc1 >= 1 && qc1 <= 192);
        o1 = min(max(qr1-1,0),191)*WW + min(max(qc1-1,0),191); g1 = v ? dr1*dc1 : 0.f; }
      { bool v = (qr0 >= 1 && qr0 <= 192 && qc1 >= 1 && qc1 <= 192);
        o2 = min(max(qr0-1,0),191)*WW + min(max(qc1-1,0),191); g2 = v ? dr0*dc1 : 0.f; }
      { bool v = (qr1 >= 1 && qr1 <= 192 && qc0 >= 1 && qc0 <= 192);
        o3 = min(max(qr1-1,0),191)*WW + min(max(qc0-1,0),191); g3 = v ? dr1*dc0 : 0.f; }
      float* dst = goL + ((size_t)n * 32 + px) * 8;
      dst[0] = g0; dst[1] = g1; dst[2] = g2; dst[3] = g3;
      int* di = (int*)(dst + 4);
      di[0] = o0; di[1] = o1; di[2] = o2; di[3] = o3;
    }
  }
  f32x16 acc[2];
  acc[0] = zero16(); acc[1] = zero16();
  const __bf16* aB = wdcA + lane * 8;
  const int po = lane >> 3, cg = lane & 7;
  const int m = lane & 31, kh8 = (lane >> 5) << 3;
#pragma unroll
  for (int n = 0; n < 9; ++n) {
    unsigned char* buf = dbuf + (n & 1) * 4608;
#pragma unroll
    for (int i = 0; i < 4; ++i) {
      int px = po * 4 + i;
      const float* gsrc = goL + ((size_t)n * 32 + px) * 8;
      f32x4 g4 = *(const f32x4*)gsrc;
      const int* oi = (const int*)(gsrc + 4);
      const __bf16* p0 = xb + (size_t)oi[0] * 64 + cg * 8;
      const __bf16* p1 = xb + (size_t)oi[1] * 64 + cg * 8;
      const __bf16* p2 = xb + (size_t)oi[2] * 64 + cg * 8;
      const __bf16* p3 = xb + (size_t)oi[3] * 64 + cg * 8;
      bf16x8 c0 = *(const bf16x8*)p0;
      bf16x8 c1 = *(const bf16x8*)p1;
      bf16x8 c2 = *(const bf16x8*)p2;
      bf16x8 c3 = *(const bf16x8*)p3;
      bf16x8 ov;
#pragma unroll
      for (int e = 0; e < 8; ++e) {
        float f = g4[0] * (float)c0[e] + g4[1] * (float)c1[e] +
                  g4[2] * (float)c2[e] + g4[3] * (float)c3[e];
        ov[e] = (__bf16)f;
      }
      *(bf16x8*)(buf + px * COLSTRIDE + cg * 16) = ov;
    }
    const unsigned char* bB = buf + m * COLSTRIDE + kh8 * 2;
#pragma unroll
    for (int kc = 0; kc < 4; ++kc) {
      bf16x8 a0 = *(const bf16x8*)(aB + ((n * 4 + kc) * 2 + 0) * 512);
      bf16x8 a1 = *(const bf16x8*)(aB + ((n * 4 + kc) * 2 + 1) * 512);
      bf16x8 b0 = *(const bf16x8*)(bB + kc * 32);
      acc[0] = mfma32(a0, b0, acc[0]);
      acc[1] = mfma32(a1, b0, acc[1]);
    }
  }
  // epilogue: transpose 32px x 64ch through LDS, store NHWC fp32
  unsigned char* reg = dbuf;
  int colb = lane & 31, half = lane >> 5;
#pragma unroll
  for (int ot = 0; ot < 2; ++ot)
#pragma unroll
    for (int g = 0; g < 4; ++g) {
      int o = ot * 32 + half * 4 + g * 8;
      f32x4 v;
      v[0] = acc[ot][g * 4 + 0]; v[1] = acc[ot][g * 4 + 1];
      v[2] = acc[ot][g * 4 + 2]; v[3] = acc[ot][g * 4 + 3];
      *(f32x4*)(reg + (colb * 68 + o) * 4) = v;
    }
  __builtin_amdgcn_s_waitcnt(0);
  int ch = half * 32;
  float* dp = xlow + ((size_t)b * HW + (size_t)h * 192 + wcol0 + colb) * 64 + ch;
#pragma unroll
  for (int q = 0; q < 8; ++q)
    *(f32x4*)(dp + q * 4) = *(const f32x4*)(reg + (colb * 68 + ch + q * 4) * 4);
}

// ---------------- convcat: chunk1 = xlow (fp32 NHWC), chunk2 = frn (bf16 NHWC) ----------------
__global__ __launch_bounds__(256, 1) void convcat_mfma(
    const float* __restrict__ xlow, const __bf16* __restrict__ frn,
    const __bf16* __restrict__ wA, const float* __restrict__ bias,
    float* __restrict__ y) {
  __shared__ __align__(16) unsigned char smem[SMEM_BYTES];
  int b = blockIdx.x / 144, r = blockIdx.x % 144, rt = r / 3, ct = r % 3;
  int h0 = rt * 4, w0 = ct * 64;
  int wid = threadIdx.x >> 6, lane = threadIdx.x & 63;
  f32x16 acc[2][2];
  acc[0][0] = zero16(); acc[0][1] = zero16(); acc[1][0] = zero16(); acc[1][1] = zero16();
  stage_f32(xlow + (size_t)b * HW * 64, 64, 0, 192, 192, h0 - 1, w0 - 1, smem);
  __syncthreads();
  kloop<8, 0>(wA, smem, wid, acc);
  __syncthreads();
  stage_bf16(frn + (size_t)b * HW * 64, 192, 192, h0 - 1, w0 - 1, smem);
  __syncthreads();
  kloop<8, 4>(wA, smem, wid, acc);
  __syncthreads();
  unsigned char* reg = smem + wid * TREG;
  float* dsty = y + ((size_t)b * HW + (size_t)(h0 + wid) * 192 + w0) * 64;
  int col = lane & 31, ch = (lane >> 5) * 32;
#pragma unroll
  for (int pt = 0; pt < 2; ++pt) {
    acchalf_to_lds(acc, pt, reg);
    __builtin_amdgcn_s_waitcnt(0);
    f32x4 v[8];
    read_half(reg, v);
    float* dp = dsty + (size_t)(pt * 32 + col) * 64 + ch;
#pragma unroll
    for (int q = 0; q < 8; ++q) {
      f32x4 bv = *(const f32x4*)(bias + ch + q * 4);
      v[q] += bv;
      *(f32x4*)(dp + q * 4) = v[q];
    }
  }
}

// ---------------- conv1 + GDN + CELU ----------------
__global__ __launch_bounds__(256, 1) void conv1gdn_mfma(
    const float* __restrict__ y, const __bf16* __restrict__ w1A,
    const __bf16* __restrict__ gA, const float* __restrict__ beta,
    __bf16* __restrict__ hbuf) {
  __shared__ __align__(16) unsigned char smem[SMEM_BYTES];
  int b = blockIdx.x / 144, r = blockIdx.x % 144, rt = r / 3, ct = r % 3;
  int h0 = rt * 4, w0 = ct * 64;
  int wid = threadIdx.x >> 6, lane = threadIdx.x & 63;
  int colb = lane & 31, half = lane >> 5;
  const int kh8 = half << 3;
  f32x16 acc[2][2];
  acc[0][0] = zero16(); acc[0][1] = zero16(); acc[1][0] = zero16(); acc[1][1] = zero16();
  stage_f32(y + (size_t)b * HW * 64, 64, 0, 192, 192, h0, w0, smem);
  __syncthreads();
  kloop<4, 0>(w1A, smem, wid, acc);
  __syncthreads();
#pragma unroll
  for (int ot = 0; ot < 2; ++ot)
#pragma unroll
    for (int pt = 0; pt < 2; ++pt)
#pragma unroll
      for (int g = 0; g < 4; ++g) {
        int o = ot * 32 + half * 4 + g * 8;
        int p = wid * 64 + pt * 32 + colb;
        bf16x4 s;
#pragma unroll
        for (int e = 0; e < 4; ++e) {
          float x = acc[ot][pt][g * 4 + e];
          s[e] = (__bf16)(x * x);
        }
        *(bf16x4*)(smem + p * GDNPITCH + o * 2) = s;
      }
  __syncthreads();
  f32x16 nacc[2][2];
  nacc[0][0] = zero16(); nacc[0][1] = zero16(); nacc[1][0] = zero16(); nacc[1][1] = zero16();
  {
    const __bf16* gaB = gA + lane * 8;
    const unsigned char* gb = smem + (wid * 64 + colb) * GDNPITCH + kh8 * 2;
#pragma unroll
    for (int kc = 0; kc < 4; ++kc) {
      bf16x8 a0 = *(const bf16x8*)(gaB + (kc * 2 + 0) * 512);
      bf16x8 a1 = *(const bf16x8*)(gaB + (kc * 2 + 1) * 512);
      bf16x8 b0 = *(const bf16x8*)(gb + kc * 32);
      bf16x8 b1 = *(const bf16x8*)(gb + 32 * GDNPITCH + kc * 32);
      nacc[0][0] = mfma32(a0, b0, nacc[0][0]);
      nacc[0][1] = mfma32(a0, b1, nacc[0][1]);
      nacc[1][0] = mfma32(a1, b0, nacc[1][0]);
      nacc[1][1] = mfma32(a1, b1, nacc[1][1]);
    }
  }
#pragma unroll
  for (int ot = 0; ot < 2; ++ot)
#pragma unroll
    for (int g = 0; g < 4; ++g) {
      f32x4 bet = *(const f32x4*)(beta + ot * 32 + half * 4 + g * 8);
#pragma unroll
      for (int pt = 0; pt < 2; ++pt)
#pragma unroll
        for (int e = 0; e < 4; ++e) {
          float nv = bet[e] + nacc[ot][pt][g * 4 + e];
          float hv = acc[ot][pt][g * 4 + e] * rsqrtf(nv);
          hv = hv > 0.f ? hv : expf(hv) - 1.f;
          acc[ot][pt][g * 4 + e] = hv;
        }
    }
  __syncthreads();
  unsigned char* reg = smem + wid * TREG;
  int hr = h0 + wid;
  bool rowok = hr < 190;
  int ch = half * 32;
#pragma unroll
  for (int pt = 0; pt < 2; ++pt) {
    acchalf_to_lds(acc, pt, reg);
    __builtin_amdgcn_s_waitcnt(0);
    f32x4 v[8];
    read_half(reg, v);
    int wcol = w0 + pt * 32 + colb;
    if (rowok && wcol < 190) {
      __bf16* dp = hbuf + ((size_t)b * HW1 + (size_t)hr * 190 + wcol) * 64 + ch;
#pragma unroll
      for (int q = 0; q < 8; ++q) {
        bf16x4 o;
#pragma unroll
        for (int e = 0; e < 4; ++e) o[e] = (__bf16)v[q][e];
        *(bf16x4*)(dp + q * 4) = o;
      }
    }
  }
}

// ---------------- conv2 (pad 2) + residual; LAST adds x and writes NCHW out ----------------
template <bool LAST>
__global__ __launch_bounds__(256, 1) void conv2_mfma(
    const __bf16* __restrict__ hbuf, const __bf16* __restrict__ w2A,
    const float* __restrict__ xlow, float* __restrict__ y,
    float* __restrict__ out) {
  __shared__ __align__(16) unsigned char smem[SMEM_BYTES];
  int b = blockIdx.x / 144, r = blockIdx.x % 144, rt = r / 3, ct = r % 3;
  int h0 = rt * 4, w0 = ct * 64;
  int wid = threadIdx.x >> 6, lane = threadIdx.x & 63;
  f32x16 acc[2][2];
  acc[0][0] = zero16(); acc[0][1] = zero16(); acc[1][0] = zero16(); acc[1][1] = zero16();
  stage_bf16(hbuf + (size_t)b * HW1 * 64, 190, 190, h0 - 2, w0 - 2, smem);
  __syncthreads();
  kloop<4, 0>(w2A, smem, wid, acc);
  __syncthreads();
  unsigned char* reg = smem + wid * TREG;
  int col = lane & 31, ch = (lane >> 5) * 32;
  size_t pixbase = (size_t)b * HW + (size_t)(h0 + wid) * 192 + w0;
#pragma unroll
  for (int pt = 0; pt < 2; ++pt) {
    acchalf_to_lds(acc, pt, reg);
    __builtin_amdgcn_s_waitcnt(0);
    f32x4 v[8];
    read_half(reg, v);
    size_t pix = pixbase + pt * 32 + col;
    float* yp = y + pix * 64 + ch;
#pragma unroll
    for (int q = 0; q < 8; ++q) v[q] += *(const f32x4*)(yp + q * 4);
    if (!LAST) {
#pragma unroll
      for (int q = 0; q < 8; ++q) *(f32x4*)(yp + q * 4) = v[q];
    } else {
      const float* xp = xlow + pix * 64 + ch;
#pragma unroll
      for (int q = 0; q < 8; ++q) v[q] += *(const f32x4*)(xp + q * 4);
#pragma unroll
      for (int q = 0; q < 8; ++q)
        *(f32x4*)(reg + (col * 68 + ch + q * 4) * 4) = v[q];
      __builtin_amdgcn_s_waitcnt(0);
      int o = lane;
      float* op = out + ((size_t)b * 64 + o) * HW + (size_t)(h0 + wid) * 192 + w0 + pt * 32;
#pragma unroll
      for (int q = 0; q < 8; ++q) {
        f32x4 s;
#pragma unroll
        for (int e = 0; e < 4; ++e)
          s[e] = *(const float*)(reg + ((q * 4 + e) * 68 + o) * 4);
        *(f32x4*)(op + q * 4) = s;
      }
    }
  }
}

extern "C" void kernel_launch(void* const* d_in, const int* in_sizes, int n_in,
                              void* d_out, int out_size, void* d_ws, size_t ws_size,
                              hipStream_t stream) {
  const float* f_r      = (const float*)d_in[0];
  const float* m_t      = (const float*)d_in[1];
  const float* w_pconv  = (const float*)d_in[2];
  const float* b_pconv  = (const float*)d_in[3];
  const float* w_dc     = (const float*)d_in[4];
  const float* w_cat    = (const float*)d_in[5];
  const float* b_cat    = (const float*)d_in[6];
  const float* rb_w1    = (const float*)d_in[7];
  const float* rb_w2    = (const float*)d_in[8];
  const float* rb_beta  = (const float*)d_in[9];
  const float* rb_gamma = (const float*)d_in[10];
  float* out = (float*)d_out;

  float* ws = (float*)d_ws;
  float*  xlow  = ws;                         // [2][HW][64] f32 (deform out = residual x)
  float*  ybuf  = xlow + 4718592;             // [2][HW][64] f32
  float*  off20 = ybuf + 4718592;             // [2][HW][20] f32
  __bf16* frn   = (__bf16*)(off20 + 1474560); // [2][HW][64] bf16
  __bf16* mtn   = (__bf16*)(off20 + 1474560 + 2359296); // bf16; aliased with hbuf
  __bf16* hbuf  = mtn;                        // mtn dead after pconv; hbuf written later
  float*  wbase = off20 + 1474560 + 2359296 + 2359296;
  __bf16* wpA   = (__bf16*)wbase;             // 18432 bf16
  __bf16* wdcA  = (__bf16*)(wbase + 9216);    // 36864 bf16
  __bf16* wcatA = (__bf16*)(wbase + 27648);   // 73728 bf16
  __bf16* w1A   = (__bf16*)(wbase + 64512);   // 110592 bf16
  __bf16* w2A   = (__bf16*)(wbase + 119808);  // 110592 bf16
  __bf16* gA    = (__bf16*)(wbase + 175104);  // 12288 bf16
  float*  bpad  = wbase + 181248;             // 20 f32

  prep_weights<<<1417, 256, 0, stream>>>(w_pconv, b_pconv, w_dc, w_cat, rb_w1, rb_w2,
                                         rb_gamma, wpA, wdcA, wcatA, w1A, w2A, gA, bpad);
  to_nhwc_bf16<<<2304, 256, 0, stream>>>(f_r, m_t, frn, mtn);
  pconv_mfma<<<288, 256, 0, stream>>>(mtn, wpA, bpad, off20);
  deform_mfma<<<1152, 128, 0, stream>>>(frn, off20, wdcA, xlow);
  convcat_mfma<<<288, 256, 0, stream>>>(xlow, frn, wcatA, b_cat, ybuf);
  for (int l = 0; l < 3; ++l) {
    conv1gdn_mfma<<<288, 256, 0, stream>>>(ybuf, w1A + l * 36864, gA + l * 4096,
                                           rb_beta + l * 64, hbuf);
    if (l < 2)
      conv2_mfma<false><<<288, 256, 0, stream>>>(hbuf, w2A + l * 36864, xlow, ybuf, out);
    else
      conv2_mfma<true><<<288, 256, 0, stream>>>(hbuf, w2A + l * 36864, xlow, ybuf, out);
  }
}